// Round 6
// baseline (1489.506 us; speedup 1.0000x reference)
//
#include <hip/hip_runtime.h>
#include <hip/hip_bf16.h>

typedef __bf16 bf16_t;
typedef __bf16 bf16x8 __attribute__((ext_vector_type(8)));
typedef float  f32x4  __attribute__((ext_vector_type(4)));

static constexpr int TT = 8192;     // tokens (2*4096)
static constexpr int DD = 1024;
static constexpr int FF = 4096;
static constexpr int NSLOT = 2 * TT;  // 16384 (token, k) slots

// routing int-array layout
#define R_COUNTS 0
#define R_OFFSET 8
#define R_TSTART 17
#define R_CURSOR 26
#define R_TOTAL  34
#define R_INTS   40

#define GLL(g, l) __builtin_amdgcn_global_load_lds( \
    (__attribute__((address_space(1))) void*)(g), \
    (__attribute__((address_space(3))) void*)(l), 16, 0, 0)

#define BARRIER asm volatile("s_barrier" ::: "memory")
#define WAITL0  do { asm volatile("s_waitcnt lgkmcnt(0)" ::: "memory"); \
                     __builtin_amdgcn_sched_barrier(0); } while (0)

__device__ __forceinline__ float fast_gelu(float v) {
  float t = -1.5957691216f * v - 0.0713548162f * (v * v * v);
  return v / (1.f + __expf(t));
}

// ---------------------------------------------------------------- convert
__global__ __launch_bounds__(256) void cvt_f32_bf16(const float* __restrict__ src,
                                                    bf16_t* __restrict__ dst, int n8) {
  int i = blockIdx.x * 256 + threadIdx.x;
  if (i >= n8) return;
  const float4* s = reinterpret_cast<const float4*>(src) + (size_t)i * 2;
  float4 a = s[0], b = s[1];
  bf16x8 v;
  v[0] = (bf16_t)a.x; v[1] = (bf16_t)a.y; v[2] = (bf16_t)a.z; v[3] = (bf16_t)a.w;
  v[4] = (bf16_t)b.x; v[5] = (bf16_t)b.y; v[6] = (bf16_t)b.z; v[7] = (bf16_t)b.w;
  *reinterpret_cast<bf16x8*>(dst + (size_t)i * 8) = v;
}

// ---------------------------------------------------------------- gate
__global__ __launch_bounds__(256) void gate_kernel(const float* __restrict__ x,
                                                   const float* __restrict__ gw,
                                                   float* __restrict__ topkw,
                                                   int* __restrict__ slote,
                                                   int* __restrict__ routing) {
  int wid = threadIdx.x >> 6, lane = threadIdx.x & 63;
  int t = blockIdx.x * 4 + wid;
  const float4* xv = reinterpret_cast<const float4*>(x + (size_t)t * DD) + lane * 4;
  const float4* gv = reinterpret_cast<const float4*>(gw);
  float acc[8];
#pragma unroll
  for (int e = 0; e < 8; ++e) acc[e] = 0.f;
#pragma unroll
  for (int i = 0; i < 4; ++i) {
    float4 xi = xv[i];
#pragma unroll
    for (int e = 0; e < 8; ++e) {
      float4 g = gv[e * 256 + lane * 4 + i];
      acc[e] += xi.x * g.x + xi.y * g.y + xi.z * g.z + xi.w * g.w;
    }
  }
#pragma unroll
  for (int e = 0; e < 8; ++e)
    for (int off = 32; off; off >>= 1) acc[e] += __shfl_xor(acc[e], off, 64);
  if (lane == 0) {
    float m = acc[0];
#pragma unroll
    for (int e = 1; e < 8; ++e) m = fmaxf(m, acc[e]);
    float p[8], s = 0.f;
#pragma unroll
    for (int e = 0; e < 8; ++e) { p[e] = expf(acc[e] - m); s += p[e]; }
    float inv = 1.f / s;
#pragma unroll
    for (int e = 0; e < 8; ++e) p[e] *= inv;
    int e1 = 0; float b1v = p[0];
#pragma unroll
    for (int e = 1; e < 8; ++e) if (p[e] > b1v) { b1v = p[e]; e1 = e; }
    int e2 = -1; float b2v = -1.f;
#pragma unroll
    for (int e = 0; e < 8; ++e) if (e != e1 && p[e] > b2v) { b2v = p[e]; e2 = e; }
    topkw[2 * t] = b1v;  topkw[2 * t + 1] = b2v;
    slote[2 * t] = e1;   slote[2 * t + 1] = e2;
    atomicAdd(&routing[R_COUNTS + e1], 1);
    atomicAdd(&routing[R_COUNTS + e2], 1);
  }
}

// ---------------------------------------------------------------- scan (1 thread)
__global__ void scan_kernel(int* __restrict__ routing) {
  int off = 0, tt = 0;
  for (int e = 0; e < 8; ++e) {
    routing[R_OFFSET + e] = off;
    routing[R_TSTART + e] = tt;
    int c = routing[R_COUNTS + e];
    off += c;
    tt += (c + 255) >> 8;   // 256-row M-tiles
    routing[R_CURSOR + e] = 0;
  }
  routing[R_OFFSET + 8] = off;
  routing[R_TSTART + 8] = tt;
  routing[R_TOTAL] = tt;
}

// ---------------------------------------------------------------- scatter
__global__ __launch_bounds__(256) void scatter_kernel(const int* __restrict__ slote,
                                                      int* __restrict__ routing,
                                                      int* __restrict__ perm,
                                                      int* __restrict__ pos) {
  int s = blockIdx.x * 256 + threadIdx.x;
  int e = slote[s];
  int p = atomicAdd(&routing[R_CURSOR + e], 1);
  int pp = routing[R_OFFSET + e] + p;
  perm[pp] = s;
  pos[s] = pp;
}

// ---------------------------------------------------------------- combine
__global__ __launch_bounds__(256) void combine_kernel(const float* __restrict__ slotbuf,
                                                      const int* __restrict__ pos,
                                                      const float* __restrict__ topkw,
                                                      float* __restrict__ out) {
  int idx = blockIdx.x * 256 + threadIdx.x;   // one float4 per thread
  int t = idx >> 8;                            // DD/4 = 256 float4 per token
  int c = (idx & 255) << 2;
  int p0 = pos[2 * t], p1 = pos[2 * t + 1];
  float w0 = topkw[2 * t], w1 = topkw[2 * t + 1];
  float4 o = *reinterpret_cast<const float4*>(&out[(size_t)t * DD + c]);
  float4 s0 = *reinterpret_cast<const float4*>(&slotbuf[(size_t)p0 * DD + c]);
  float4 s1 = *reinterpret_cast<const float4*>(&slotbuf[(size_t)p1 * DD + c]);
  o.x += w0 * s0.x + w1 * s1.x;
  o.y += w0 * s0.y + w1 * s1.y;
  o.z += w0 * s0.z + w1 * s1.z;
  o.w += w0 * s0.w + w1 * s1.w;
  *reinterpret_cast<float4*>(&out[(size_t)t * DD + c]) = o;
}

// ---------------------------------------------------------------- GEMM (8-phase 256x256, BK=64, dbuf)
// Staging order (latency-proofed): B(kt+1) halves at phases 0/1 (contiguous, 4-phase
// lead); A(kt+2) as four 64-row QUARTERS at phases 1/2/3/0-of-next (7-phase lead for the
// gathered A). Quarter q covers rows {q*32..q*32+31} u {128+q*32..}, i.e. exactly the
// m(2q),m(2q+1) rows consumed in phase q -> staging it >=1 barrier later is race-free.
// Per-tile vmcnt(3): the 3 newest GLLs (A(kt+2) q0-q2) stay in flight; everything tile
// kt+1 reads is guaranteed landed.
template <int MODE>
__global__ __launch_bounds__(512, 2) void gemm_kernel(
    const bf16_t* __restrict__ A, const bf16_t* __restrict__ Bw,
    const float* __restrict__ bias, bf16_t* __restrict__ Hout,
    float* __restrict__ out, const int* __restrict__ routing,
    const int* __restrict__ perm) {
  constexpr bool G1 = (MODE == 0 || MODE == 2);
  constexpr bool EXPERT = (MODE < 2);
  constexpr int K = G1 ? 1024 : 4096;
  constexpr int NTOT = G1 ? 4096 : 1024;
  constexpr int NT = NTOT / 256;   // 16 or 4
  constexpr int NKT = K / 64;      // 16 or 64

  __shared__ __align__(16) bf16_t lds[2 * 32768];   // 128 KB

  const int t = threadIdx.x;
  const int lane = t & 63;
  const int wid = t >> 6;          // 0..7
  const int wm = wid >> 2;         // 0..1  (128-row half)
  const int wn = wid & 3;          // 0..3  (64-col quarter)

  // ---- block decode: bijective XCD swizzle, nt-fastest
  const int nwg = gridDim.x;
  const int q = nwg >> 3, r = nwg & 7;
  const int xcd = blockIdx.x & 7, bi = blockIdx.x >> 3;
  const int swz = (xcd < r ? xcd * (q + 1) : r * (q + 1) + (xcd - r) * q) + bi;
  const int mt = swz / NT;
  const int nt = swz % NT;

  int row0, valid, eidx = 0;
  if constexpr (EXPERT) {
    if (mt >= routing[R_TOTAL]) return;
    int e = 0;
    while (e < 7 && routing[R_TSTART + e + 1] <= mt) ++e;
    eidx = e;
    int lm = mt - routing[R_TSTART + e];
    row0 = routing[R_OFFSET + e] + lm * 256;
    valid = min(256, routing[R_COUNTS + e] - lm * 256);
  } else {
    row0 = mt * 256;
    valid = 256;
  }

  const bf16_t* Bexp = Bw + (EXPERT ? (size_t)eidx * NTOT * K : 0);
  const float* biasp = bias + (EXPERT ? eidx * NTOT : 0);

  // ---- staging addressing
  // A quarters: sub = t>>3 (0..63); rbase = (sub&31) + ((sub>>5)<<7); row(q) = q*32+rbase
  // phys chunk = t&7 at LDS; logical source chunk = (t&7) ^ (row&7) = (t&7)^((t>>3)&7)
  const int sub = t >> 3;
  const int rbase = (sub & 31) + ((sub >> 5) << 7);
  const int lc = (t & 7) ^ (sub & 7);
  const bf16_t* aQ[4];
#pragma unroll
  for (int qq = 0; qq < 4; ++qq) {
    int lr = qq * 32 + rbase;
    int gr;
    if constexpr (MODE == 0) {
      gr = perm[row0 + min(lr, valid - 1)] >> 1;
    } else if constexpr (MODE == 1) {
      gr = row0 + min(lr, valid - 1);
    } else {
      gr = row0 + lr;
    }
    aQ[qq] = A + (size_t)gr * K + lc * 8;
  }
  // B halves: rows sr + {0,64} (half0) / {128,192} (half1), sr = t>>3
  const bf16_t* bS[4];
#pragma unroll
  for (int i = 0; i < 4; ++i)
    bS[i] = Bexp + (size_t)(nt * 256 + sub + i * 64) * K + lc * 8;

  auto stageAq = [&](int j, int qq) {
    bf16_t* d = lds + ((j & 1) << 15) + (((qq << 5) + rbase) << 6) + ((t & 7) << 3);
    GLL(aQ[qq] + (size_t)j * 64, d);
  };
  auto stageB = [&](int j, int half) {
    bf16_t* d = lds + ((j & 1) << 15) + 16384 + (half << 13) + (t << 3);
    size_t kof = (size_t)j * 64;
    GLL(bS[half * 2 + 0] + kof, d);
    GLL(bS[half * 2 + 1] + kof, d + 4096);
  };

  // ---- fragment read offsets (elements)
  const int xorv = lane & 7;
  const int kgrp = lane >> 4;
  const int ck0 = ((kgrp) ^ xorv) << 3;
  const int ck1 = ((kgrp + 4) ^ xorv) << 3;
  const int aBase = (wm << 13) + ((lane & 15) << 6);
  const int bBase = 16384 + ((wn >> 1) << 13) + ((wn & 1) << 12) + ((lane & 15) << 6);

  f32x4 acc[8][4];
#pragma unroll
  for (int m = 0; m < 8; ++m)
#pragma unroll
    for (int n = 0; n < 4; ++n) acc[m][n] = f32x4{0.f, 0.f, 0.f, 0.f};

#define PHASE_READ_A(M0)                                                                       \
  _Pragma("unroll") for (int mm = 0; mm < 2; ++mm) {                                           \
    af[mm][0] = *reinterpret_cast<const bf16x8*>(&lds[bufOfs + aBase + (M0 + mm) * 1024 + ck0]); \
    af[mm][1] = *reinterpret_cast<const bf16x8*>(&lds[bufOfs + aBase + (M0 + mm) * 1024 + ck1]); \
  }

#define PHASE_MFMA(M0)                                                                     \
  __builtin_amdgcn_s_setprio(1);                                                           \
  _Pragma("unroll") for (int mm = 0; mm < 2; ++mm)                                         \
  _Pragma("unroll") for (int n = 0; n < 4; ++n) {                                          \
    acc[M0 + mm][n] = __builtin_amdgcn_mfma_f32_16x16x32_bf16(af[mm][0], bfr[n][0],        \
                                                              acc[M0 + mm][n], 0, 0, 0);  \
    acc[M0 + mm][n] = __builtin_amdgcn_mfma_f32_16x16x32_bf16(af[mm][1], bfr[n][1],        \
                                                              acc[M0 + mm][n], 0, 0, 0);  \
  }                                                                                        \
  __builtin_amdgcn_s_setprio(0);

  // ---- prologue: A(0)+B(0) full, A(1) q0-q2; wait until only A(1)q0-2 in flight
  stageAq(0, 0); stageAq(0, 1); stageAq(0, 2); stageAq(0, 3);
  stageB(0, 0); stageB(0, 1);
  stageAq(1, 0); stageAq(1, 1); stageAq(1, 2);
  asm volatile("s_waitcnt vmcnt(3)" ::: "memory");
  BARRIER;

  bf16x8 bfr[4][2];
  for (int kt = 0; kt < NKT; ++kt) {
    const int bufOfs = (kt & 1) << 15;
    bf16x8 af[2][2];

    // phase 0: all B + A m0,m1; stage B(kt+1)-low and A(kt+1)q3
#pragma unroll
    for (int n = 0; n < 4; ++n) {
      bfr[n][0] = *reinterpret_cast<const bf16x8*>(&lds[bufOfs + bBase + n * 1024 + ck0]);
      bfr[n][1] = *reinterpret_cast<const bf16x8*>(&lds[bufOfs + bBase + n * 1024 + ck1]);
    }
    PHASE_READ_A(0)
    if (kt + 1 < NKT) { stageB(kt + 1, 0); stageAq(kt + 1, 3); }
    BARRIER; WAITL0;
    PHASE_MFMA(0)
    BARRIER;

    // phase 1: A m2,m3; stage B(kt+1)-high and A(kt+2)q0
    PHASE_READ_A(2)
    if (kt + 1 < NKT) stageB(kt + 1, 1);
    if (kt + 2 < NKT) stageAq(kt + 2, 0);
    BARRIER; WAITL0;
    PHASE_MFMA(2)
    BARRIER;

    // phase 2: A m4,m5; stage A(kt+2)q1
    PHASE_READ_A(4)
    if (kt + 2 < NKT) stageAq(kt + 2, 1);
    BARRIER; WAITL0;
    PHASE_MFMA(4)
    BARRIER;

    // phase 3: A m6,m7; stage A(kt+2)q2; counted end-of-tile wait
    PHASE_READ_A(6)
    if (kt + 2 < NKT) stageAq(kt + 2, 2);
    if (kt + 1 < NKT) {
      if (kt + 2 < NKT) { asm volatile("s_waitcnt vmcnt(3)" ::: "memory"); }
      else              { asm volatile("s_waitcnt vmcnt(0)" ::: "memory"); }
    }
    BARRIER; WAITL0;
    PHASE_MFMA(6)
    BARRIER;
  }

  // ---- epilogue.  C/D: col = lane&15, row = (lane>>4)*4 + reg
  if constexpr (G1) {
#pragma unroll
    for (int n = 0; n < 4; ++n) {
      int col = nt * 256 + wn * 64 + n * 16 + (lane & 15);
      float bc = biasp[col];
#pragma unroll
      for (int m = 0; m < 8; ++m) {
        int lrb = wm * 128 + m * 16 + ((lane >> 4) << 2);
#pragma unroll
        for (int rr = 0; rr < 4; ++rr) {
          int lr = lrb + rr;
          if (lr < valid) {
            float v = acc[m][n][rr] + bc;
            Hout[(size_t)(row0 + lr) * FF + col] = (bf16_t)fast_gelu(v);
          }
        }
      }
    }
  } else {
#pragma unroll
    for (int m = 0; m < 8; ++m) {
      int lrb = wm * 128 + m * 16 + ((lane >> 4) << 2);
#pragma unroll
      for (int rr = 0; rr < 4; ++rr) {
        int lr = lrb + rr;
        if (lr >= valid) continue;
#pragma unroll
        for (int n = 0; n < 4; ++n) {
          int col = nt * 256 + wn * 64 + n * 16 + (lane & 15);
          out[(size_t)(row0 + lr) * DD + col] = acc[m][n][rr] + biasp[col];
        }
      }
    }
  }
}

// ---------------------------------------------------------------- probes (diagnostic; write dead scratch)
// PV=0: full pipeline, DIRECT contiguous A (gather attribution vs real expert-G1)
// PV=2: no mid-loop staging (stale LDS reuse) -> skeleton+epilogue floor
template <int PV>
__global__ __launch_bounds__(512, 2) void probe_kernel(
    const bf16_t* __restrict__ A, const bf16_t* __restrict__ Bw,
    const float* __restrict__ bias, bf16_t* __restrict__ Hout) {
  constexpr int K = 1024;
  constexpr int NT = 16;
  constexpr int NKT = 16;
  __shared__ __align__(16) bf16_t lds[2 * 32768];

  const int t = threadIdx.x;
  const int lane = t & 63;
  const int wid = t >> 6;
  const int wm = wid >> 2;
  const int wn = wid & 3;

  const int nwg = gridDim.x;
  const int q = nwg >> 3, r = nwg & 7;
  const int xcd = blockIdx.x & 7, bi = blockIdx.x >> 3;
  const int swz = (xcd < r ? xcd * (q + 1) : r * (q + 1) + (xcd - r) * q) + bi;
  const int mt = swz / NT;
  const int nt = swz % NT;
  const int row0 = mt * 256;

  const int sub = t >> 3;
  const int rbase = (sub & 31) + ((sub >> 5) << 7);
  const int lc = (t & 7) ^ (sub & 7);
  const bf16_t* aQ[4];
#pragma unroll
  for (int qq = 0; qq < 4; ++qq)
    aQ[qq] = A + (size_t)(row0 + qq * 32 + rbase) * K + lc * 8;
  const bf16_t* bS[4];
#pragma unroll
  for (int i = 0; i < 4; ++i)
    bS[i] = Bw + (size_t)(nt * 256 + sub + i * 64) * K + lc * 8;

  auto stageAq = [&](int j, int qq) {
    bf16_t* d = lds + ((j & 1) << 15) + (((qq << 5) + rbase) << 6) + ((t & 7) << 3);
    GLL(aQ[qq] + (size_t)j * 64, d);
  };
  auto stageB = [&](int j, int half) {
    bf16_t* d = lds + ((j & 1) << 15) + 16384 + (half << 13) + (t << 3);
    size_t kof = (size_t)j * 64;
    GLL(bS[half * 2 + 0] + kof, d);
    GLL(bS[half * 2 + 1] + kof, d + 4096);
  };

  const int xorv = lane & 7;
  const int kgrp = lane >> 4;
  const int ck0 = ((kgrp) ^ xorv) << 3;
  const int ck1 = ((kgrp + 4) ^ xorv) << 3;
  const int aBase = (wm << 13) + ((lane & 15) << 6);
  const int bBase = 16384 + ((wn >> 1) << 13) + ((wn & 1) << 12) + ((lane & 15) << 6);

  f32x4 acc[8][4];
#pragma unroll
  for (int m = 0; m < 8; ++m)
#pragma unroll
    for (int n = 0; n < 4; ++n) acc[m][n] = f32x4{0.f, 0.f, 0.f, 0.f};

  stageAq(0, 0); stageAq(0, 1); stageAq(0, 2); stageAq(0, 3);
  stageB(0, 0); stageB(0, 1);
  stageAq(1, 0); stageAq(1, 1); stageAq(1, 2);
  asm volatile("s_waitcnt vmcnt(3)" ::: "memory");
  BARRIER;

  bf16x8 bfr[4][2];
  for (int kt = 0; kt < NKT; ++kt) {
    const int bufOfs = (kt & 1) << 15;
    bf16x8 af[2][2];
#pragma unroll
    for (int n = 0; n < 4; ++n) {
      bfr[n][0] = *reinterpret_cast<const bf16x8*>(&lds[bufOfs + bBase + n * 1024 + ck0]);
      bfr[n][1] = *reinterpret_cast<const bf16x8*>(&lds[bufOfs + bBase + n * 1024 + ck1]);
    }
    PHASE_READ_A(0)
    if constexpr (PV != 2) { if (kt + 1 < NKT) { stageB(kt + 1, 0); stageAq(kt + 1, 3); } }
    BARRIER; WAITL0;
    PHASE_MFMA(0)
    BARRIER;

    PHASE_READ_A(2)
    if constexpr (PV != 2) {
      if (kt + 1 < NKT) stageB(kt + 1, 1);
      if (kt + 2 < NKT) stageAq(kt + 2, 0);
    }
    BARRIER; WAITL0;
    PHASE_MFMA(2)
    BARRIER;

    PHASE_READ_A(4)
    if constexpr (PV != 2) { if (kt + 2 < NKT) stageAq(kt + 2, 1); }
    BARRIER; WAITL0;
    PHASE_MFMA(4)
    BARRIER;

    PHASE_READ_A(6)
    if constexpr (PV != 2) { if (kt + 2 < NKT) stageAq(kt + 2, 2); }
    if (kt + 1 < NKT) {
      if (kt + 2 < NKT) { asm volatile("s_waitcnt vmcnt(3)" ::: "memory"); }
      else              { asm volatile("s_waitcnt vmcnt(0)" ::: "memory"); }
    }
    BARRIER; WAITL0;
    PHASE_MFMA(6)
    BARRIER;
  }

#pragma unroll
  for (int n = 0; n < 4; ++n) {
    int col = nt * 256 + wn * 64 + n * 16 + (lane & 15);
    float bc = bias[col];
#pragma unroll
    for (int m = 0; m < 8; ++m) {
      int lrb = wm * 128 + m * 16 + ((lane >> 4) << 2);
#pragma unroll
      for (int rr = 0; rr < 4; ++rr) {
        float v = acc[m][n][rr] + bc;
        Hout[(size_t)((row0 + lrb + rr) & 16383) * FF + col] = (bf16_t)fast_gelu(v);
      }
    }
  }
}

#undef PHASE_READ_A
#undef PHASE_MFMA

// ---------------------------------------------------------------- launch
extern "C" void kernel_launch(void* const* d_in, const int* in_sizes, int n_in,
                              void* d_out, int out_size, void* d_ws, size_t ws_size,
                              hipStream_t stream) {
  const float* x   = (const float*)d_in[0];
  const float* gw  = (const float*)d_in[1];
  const float* w1  = (const float*)d_in[2];
  const float* b1  = (const float*)d_in[3];
  const float* w2  = (const float*)d_in[4];
  const float* b2  = (const float*)d_in[5];
  const float* sw1 = (const float*)d_in[6];
  const float* sb1 = (const float*)d_in[7];
  const float* sw2 = (const float*)d_in[8];
  const float* sb2 = (const float*)d_in[9];
  float* out = (float*)d_out;

  char* ws = (char*)d_ws;
  bf16_t* xb    = (bf16_t*)(ws);                          // 16 MB  [dead after expert G1]
  bf16_t* w1b   = (bf16_t*)(ws + ((size_t)16 << 20));     // 64 MB  [dead after expert G1]
  bf16_t* w2b   = (bf16_t*)(ws + ((size_t)80 << 20));     // 64 MB
  bf16_t* sw1b  = (bf16_t*)(ws + ((size_t)144 << 20));    // 8 MB
  bf16_t* sw2b  = (bf16_t*)(ws + ((size_t)152 << 20));    // 8 MB
  bf16_t* Hbuf  = (bf16_t*)(ws + ((size_t)160 << 20));    // 128 MB (16384 x 4096 bf16)
  float*  slotbuf = (float*)(ws);                         // 67 MB, overlaps xb+w1b (dead by then)
  float*  topkw = (float*)(ws + ((size_t)288 << 20));     // 64 KB
  int*    slote = (int*)(ws + ((size_t)288 << 20) + 65536);
  int*    perm  = (int*)(ws + ((size_t)288 << 20) + 2 * 65536);
  int*    pos   = (int*)(ws + ((size_t)288 << 20) + 3 * 65536);
  int*    routing = (int*)(ws + ((size_t)288 << 20) + 4 * 65536);

  hipMemsetAsync(routing, 0, R_INTS * sizeof(int), stream);

  // fp32 -> bf16 conversions
  cvt_f32_bf16<<<(TT * DD / 8 + 255) / 256, 256, 0, stream>>>(x, xb, TT * DD / 8);
  cvt_f32_bf16<<<(8 * FF * DD / 8 + 255) / 256, 256, 0, stream>>>(w1, w1b, 8 * FF * DD / 8);
  cvt_f32_bf16<<<(8 * DD * FF / 8 + 255) / 256, 256, 0, stream>>>(w2, w2b, 8 * DD * FF / 8);
  cvt_f32_bf16<<<(FF * DD / 8 + 255) / 256, 256, 0, stream>>>(sw1, sw1b, FF * DD / 8);
  cvt_f32_bf16<<<(DD * FF / 8 + 255) / 256, 256, 0, stream>>>(sw2, sw2b, DD * FF / 8);

  // routing
  gate_kernel<<<TT / 4, 256, 0, stream>>>(x, gw, topkw, slote, routing);
  scan_kernel<<<1, 1, 0, stream>>>(routing);
  scatter_kernel<<<NSLOT / 256, 256, 0, stream>>>(slote, routing, perm, pos);

  // shared expert first (plain store covers all of out), then experts into slotbuf
  gemm_kernel<2><<<32 * 16, 512, 0, stream>>>(xb, sw1b, sb1, Hbuf, out, routing, perm);
  gemm_kernel<3><<<32 * 4, 512, 0, stream>>>(Hbuf, sw2b, sb2, nullptr, out, routing, perm);
  gemm_kernel<0><<<72 * 16, 512, 0, stream>>>(xb, w1b, b1, Hbuf, out, routing, perm);
  gemm_kernel<1><<<72 * 4, 512, 0, stream>>>(Hbuf, w2b, b2, nullptr, slotbuf, routing, perm);

  // out += gate-weighted expert contributions
  combine_kernel<<<TT, 256, 0, stream>>>(slotbuf, pos, topkw, out);

  // diagnostic probes (outputs dead; read-only on live buffers)
  probe_kernel<0><<<72 * 16, 512, 0, stream>>>((const bf16_t*)w2b, sw1b, sb1, Hbuf);
  probe_kernel<2><<<72 * 16, 512, 0, stream>>>((const bf16_t*)w2b, sw1b, sb1, Hbuf);
}

// Round 7
// 1084.994 us; speedup vs baseline: 1.3728x; 1.3728x over previous
//
#include <hip/hip_runtime.h>
#include <hip/hip_bf16.h>

typedef __bf16 bf16_t;
typedef __bf16 bf16x8 __attribute__((ext_vector_type(8)));
typedef float  f32x4  __attribute__((ext_vector_type(4)));

static constexpr int TT = 8192;     // tokens (2*4096)
static constexpr int DD = 1024;
static constexpr int FF = 4096;
static constexpr int NSLOT = 2 * TT;  // 16384 (token, k) slots

// routing int-array layout
#define R_COUNTS 0
#define R_OFFSET 8
#define R_TSTART 17
#define R_CURSOR 26
#define R_TOTAL  34
#define R_INTS   40

#define GLL(g, l) __builtin_amdgcn_global_load_lds( \
    (__attribute__((address_space(1))) void*)(g), \
    (__attribute__((address_space(3))) void*)(l), 16, 0, 0)

#define BARRIER asm volatile("s_barrier" ::: "memory")
#define WAITL0  do { asm volatile("s_waitcnt lgkmcnt(0)" ::: "memory"); \
                     __builtin_amdgcn_sched_barrier(0); } while (0)

// inline-asm LDS read: opaque to the compiler's vmcnt alias tracking (the
// GLL destinations can't be disambiguated from C++ LDS loads, which makes
// hipcc insert conservative waits). addr = 32-bit LDS byte offset.
__device__ __forceinline__ bf16x8 ds_r128(uint32_t addr) {
  bf16x8 r;
  asm volatile("ds_read_b128 %0, %1" : "=v"(r) : "v"(addr));
  return r;
}

__device__ __forceinline__ float fast_gelu(float v) {
  float t = -1.5957691216f * v - 0.0713548162f * (v * v * v);
  return v / (1.f + __expf(t));
}

// ---------------------------------------------------------------- convert
__global__ __launch_bounds__(256) void cvt_f32_bf16(const float* __restrict__ src,
                                                    bf16_t* __restrict__ dst, int n8) {
  int i = blockIdx.x * 256 + threadIdx.x;
  if (i >= n8) return;
  const float4* s = reinterpret_cast<const float4*>(src) + (size_t)i * 2;
  float4 a = s[0], b = s[1];
  bf16x8 v;
  v[0] = (bf16_t)a.x; v[1] = (bf16_t)a.y; v[2] = (bf16_t)a.z; v[3] = (bf16_t)a.w;
  v[4] = (bf16_t)b.x; v[5] = (bf16_t)b.y; v[6] = (bf16_t)b.z; v[7] = (bf16_t)b.w;
  *reinterpret_cast<bf16x8*>(dst + (size_t)i * 8) = v;
}

// ---------------------------------------------------------------- gate
__global__ __launch_bounds__(256) void gate_kernel(const float* __restrict__ x,
                                                   const float* __restrict__ gw,
                                                   float* __restrict__ topkw,
                                                   int* __restrict__ slote,
                                                   int* __restrict__ routing) {
  int wid = threadIdx.x >> 6, lane = threadIdx.x & 63;
  int t = blockIdx.x * 4 + wid;
  const float4* xv = reinterpret_cast<const float4*>(x + (size_t)t * DD) + lane * 4;
  const float4* gv = reinterpret_cast<const float4*>(gw);
  float acc[8];
#pragma unroll
  for (int e = 0; e < 8; ++e) acc[e] = 0.f;
#pragma unroll
  for (int i = 0; i < 4; ++i) {
    float4 xi = xv[i];
#pragma unroll
    for (int e = 0; e < 8; ++e) {
      float4 g = gv[e * 256 + lane * 4 + i];
      acc[e] += xi.x * g.x + xi.y * g.y + xi.z * g.z + xi.w * g.w;
    }
  }
#pragma unroll
  for (int e = 0; e < 8; ++e)
    for (int off = 32; off; off >>= 1) acc[e] += __shfl_xor(acc[e], off, 64);
  if (lane == 0) {
    float m = acc[0];
#pragma unroll
    for (int e = 1; e < 8; ++e) m = fmaxf(m, acc[e]);
    float p[8], s = 0.f;
#pragma unroll
    for (int e = 0; e < 8; ++e) { p[e] = expf(acc[e] - m); s += p[e]; }
    float inv = 1.f / s;
#pragma unroll
    for (int e = 0; e < 8; ++e) p[e] *= inv;
    int e1 = 0; float b1v = p[0];
#pragma unroll
    for (int e = 1; e < 8; ++e) if (p[e] > b1v) { b1v = p[e]; e1 = e; }
    int e2 = -1; float b2v = -1.f;
#pragma unroll
    for (int e = 0; e < 8; ++e) if (e != e1 && p[e] > b2v) { b2v = p[e]; e2 = e; }
    topkw[2 * t] = b1v;  topkw[2 * t + 1] = b2v;
    slote[2 * t] = e1;   slote[2 * t + 1] = e2;
    atomicAdd(&routing[R_COUNTS + e1], 1);
    atomicAdd(&routing[R_COUNTS + e2], 1);
  }
}

// ---------------------------------------------------------------- scan (1 thread)
__global__ void scan_kernel(int* __restrict__ routing) {
  int off = 0, tt = 0;
  for (int e = 0; e < 8; ++e) {
    routing[R_OFFSET + e] = off;
    routing[R_TSTART + e] = tt;
    int c = routing[R_COUNTS + e];
    off += c;
    tt += (c + 255) >> 8;   // 256-row M-tiles
    routing[R_CURSOR + e] = 0;
  }
  routing[R_OFFSET + 8] = off;
  routing[R_TSTART + 8] = tt;
  routing[R_TOTAL] = tt;
}

// ---------------------------------------------------------------- scatter
__global__ __launch_bounds__(256) void scatter_kernel(const int* __restrict__ slote,
                                                      int* __restrict__ routing,
                                                      int* __restrict__ perm,
                                                      int* __restrict__ pos) {
  int s = blockIdx.x * 256 + threadIdx.x;
  int e = slote[s];
  int p = atomicAdd(&routing[R_CURSOR + e], 1);
  int pp = routing[R_OFFSET + e] + p;
  perm[pp] = s;
  pos[s] = pp;
}

// ---------------------------------------------------------------- combine
__global__ __launch_bounds__(256) void combine_kernel(const float* __restrict__ slotbuf,
                                                      const int* __restrict__ pos,
                                                      const float* __restrict__ topkw,
                                                      float* __restrict__ out) {
  int idx = blockIdx.x * 256 + threadIdx.x;   // one float4 per thread
  int t = idx >> 8;                            // DD/4 = 256 float4 per token
  int c = (idx & 255) << 2;
  int p0 = pos[2 * t], p1 = pos[2 * t + 1];
  float w0 = topkw[2 * t], w1 = topkw[2 * t + 1];
  float4 o = *reinterpret_cast<const float4*>(&out[(size_t)t * DD + c]);
  float4 s0 = *reinterpret_cast<const float4*>(&slotbuf[(size_t)p0 * DD + c]);
  float4 s1 = *reinterpret_cast<const float4*>(&slotbuf[(size_t)p1 * DD + c]);
  o.x += w0 * s0.x + w1 * s1.x;
  o.y += w0 * s0.y + w1 * s1.y;
  o.z += w0 * s0.z + w1 * s1.z;
  o.w += w0 * s0.w + w1 * s1.w;
  *reinterpret_cast<float4*>(&out[(size_t)t * DD + c]) = o;
}

// ---------------------------------------------------------------- GEMM (8-phase 256x256, BK=64, dbuf)
// MODE 0: expert G1 (A gathered via perm, K=1024) -> fast_gelu -> H (bf16)
// MODE 1: expert G2 (A = H rows, K=4096)          -> (.+b2) store slotbuf fp32
// MODE 2: shared G1 (A = x direct, K=1024)        -> fast_gelu -> H (bf16)
// MODE 3: shared G2 (A = H rows, K=4096)          -> plain store out (+sb2)
//
// All in-loop fragment loads are inline-asm ds_read_b128 (no compiler-inserted
// vmcnt aliasing waits vs global_load_lds); completion enforced by the explicit
// lgkmcnt(0)+sched_barrier fence before each MFMA cluster (rule #18).
template <int MODE>
__global__ __launch_bounds__(512, 2) void gemm_kernel(
    const bf16_t* __restrict__ A, const bf16_t* __restrict__ Bw,
    const float* __restrict__ bias, bf16_t* __restrict__ Hout,
    float* __restrict__ out, const int* __restrict__ routing,
    const int* __restrict__ perm) {
  constexpr bool G1 = (MODE == 0 || MODE == 2);
  constexpr bool EXPERT = (MODE < 2);
  constexpr int K = G1 ? 1024 : 4096;
  constexpr int NTOT = G1 ? 4096 : 1024;
  constexpr int NT = NTOT / 256;   // 16 or 4
  constexpr int NKT = K / 64;      // 16 or 64

  __shared__ __align__(16) bf16_t lds[2 * 32768];   // 128 KB

  const int t = threadIdx.x;
  const int lane = t & 63;
  const int wid = t >> 6;          // 0..7
  const int wm = wid >> 2;         // 0..1  (128-row half)
  const int wn = wid & 3;          // 0..3  (64-col quarter)

  // ---- block decode: bijective XCD swizzle, nt-fastest
  const int nwg = gridDim.x;
  const int q = nwg >> 3, r = nwg & 7;
  const int xcd = blockIdx.x & 7, bi = blockIdx.x >> 3;
  const int swz = (xcd < r ? xcd * (q + 1) : r * (q + 1) + (xcd - r) * q) + bi;
  const int mt = swz / NT;
  const int nt = swz % NT;

  int row0, valid, eidx = 0;
  if constexpr (EXPERT) {
    if (mt >= routing[R_TOTAL]) return;
    int e = 0;
    while (e < 7 && routing[R_TSTART + e + 1] <= mt) ++e;
    eidx = e;
    int lm = mt - routing[R_TSTART + e];
    row0 = routing[R_OFFSET + e] + lm * 256;
    valid = min(256, routing[R_COUNTS + e] - lm * 256);
  } else {
    row0 = mt * 256;
    valid = 256;
  }

  const bf16_t* Bexp = Bw + (EXPERT ? (size_t)eidx * NTOT * K : 0);
  const float* biasp = bias + (EXPERT ? eidx * NTOT : 0);

  // ---- staging addressing
  // A quarters: sub = t>>3 (0..63); rbase = (sub&31) + ((sub>>5)<<7); row(q) = q*32+rbase
  // phys chunk = t&7 at LDS; logical source chunk = (t&7) ^ (row&7) = (t&7)^((t>>3)&7)
  const int sub = t >> 3;
  const int rbase = (sub & 31) + ((sub >> 5) << 7);
  const int lc = (t & 7) ^ (sub & 7);
  const bf16_t* aQ[4];
#pragma unroll
  for (int qq = 0; qq < 4; ++qq) {
    int lr = qq * 32 + rbase;
    int gr;
    if constexpr (MODE == 0) {
      gr = perm[row0 + min(lr, valid - 1)] >> 1;
    } else if constexpr (MODE == 1) {
      gr = row0 + min(lr, valid - 1);
    } else {
      gr = row0 + lr;
    }
    aQ[qq] = A + (size_t)gr * K + lc * 8;
  }
  // B halves: rows sub + {0,64} (half0) / {128,192} (half1)
  const bf16_t* bS[4];
#pragma unroll
  for (int i = 0; i < 4; ++i)
    bS[i] = Bexp + (size_t)(nt * 256 + sub + i * 64) * K + lc * 8;

  auto stageAq = [&](int j, int qq) {
    bf16_t* d = lds + ((j & 1) << 15) + (((qq << 5) + rbase) << 6) + ((t & 7) << 3);
    GLL(aQ[qq] + (size_t)j * 64, d);
  };
  auto stageB = [&](int j, int half) {
    bf16_t* d = lds + ((j & 1) << 15) + 16384 + (half << 13) + (t << 3);
    size_t kof = (size_t)j * 64;
    GLL(bS[half * 2 + 0] + kof, d);
    GLL(bS[half * 2 + 1] + kof, d + 4096);
  };

  // ---- fragment read offsets (elements); asm reads use byte addresses
  const uint32_t ldsbase = (uint32_t)(uintptr_t)(&lds[0]);
  const int xorv = lane & 7;
  const int kgrp = lane >> 4;
  const int ck0 = ((kgrp) ^ xorv) << 3;
  const int ck1 = ((kgrp + 4) ^ xorv) << 3;
  const int aBase = (wm << 13) + ((lane & 15) << 6);
  const int bBase = 16384 + ((wn >> 1) << 13) + ((wn & 1) << 12) + ((lane & 15) << 6);

  f32x4 acc[8][4];
#pragma unroll
  for (int m = 0; m < 8; ++m)
#pragma unroll
    for (int n = 0; n < 4; ++n) acc[m][n] = f32x4{0.f, 0.f, 0.f, 0.f};

#define PHASE_READ_A(M0)                                                                     \
  _Pragma("unroll") for (int mm = 0; mm < 2; ++mm) {                                         \
    af[mm][0] = ds_r128(ldsbase + bufByte + ((uint32_t)(aBase + (M0 + mm) * 1024 + ck0) << 1)); \
    af[mm][1] = ds_r128(ldsbase + bufByte + ((uint32_t)(aBase + (M0 + mm) * 1024 + ck1) << 1)); \
  }

#define PHASE_MFMA(M0)                                                                     \
  __builtin_amdgcn_s_setprio(1);                                                           \
  _Pragma("unroll") for (int mm = 0; mm < 2; ++mm)                                         \
  _Pragma("unroll") for (int n = 0; n < 4; ++n) {                                          \
    acc[M0 + mm][n] = __builtin_amdgcn_mfma_f32_16x16x32_bf16(af[mm][0], bfr[n][0],        \
                                                              acc[M0 + mm][n], 0, 0, 0);  \
    acc[M0 + mm][n] = __builtin_amdgcn_mfma_f32_16x16x32_bf16(af[mm][1], bfr[n][1],        \
                                                              acc[M0 + mm][n], 0, 0, 0);  \
  }                                                                                        \
  __builtin_amdgcn_s_setprio(0);

  // ---- prologue: A(0)+B(0) full, A(1) q0-q2; wait until only A(1)q0-2 in flight
  stageAq(0, 0); stageAq(0, 1); stageAq(0, 2); stageAq(0, 3);
  stageB(0, 0); stageB(0, 1);
  stageAq(1, 0); stageAq(1, 1); stageAq(1, 2);
  asm volatile("s_waitcnt vmcnt(3)" ::: "memory");
  BARRIER;

  bf16x8 bfr[4][2];
  for (int kt = 0; kt < NKT; ++kt) {
    const uint32_t bufByte = (uint32_t)(kt & 1) << 16;
    bf16x8 af[2][2];

    // phase 0: all B + A m0,m1; stage B(kt+1)-low and A(kt+1)q3
#pragma unroll
    for (int n = 0; n < 4; ++n) {
      bfr[n][0] = ds_r128(ldsbase + bufByte + ((uint32_t)(bBase + n * 1024 + ck0) << 1));
      bfr[n][1] = ds_r128(ldsbase + bufByte + ((uint32_t)(bBase + n * 1024 + ck1) << 1));
    }
    PHASE_READ_A(0)
    if (kt + 1 < NKT) { stageB(kt + 1, 0); stageAq(kt + 1, 3); }
    BARRIER; WAITL0;
    PHASE_MFMA(0)
    BARRIER;

    // phase 1: A m2,m3; stage B(kt+1)-high and A(kt+2)q0
    PHASE_READ_A(2)
    if (kt + 1 < NKT) stageB(kt + 1, 1);
    if (kt + 2 < NKT) stageAq(kt + 2, 0);
    BARRIER; WAITL0;
    PHASE_MFMA(2)
    BARRIER;

    // phase 2: A m4,m5; stage A(kt+2)q1
    PHASE_READ_A(4)
    if (kt + 2 < NKT) stageAq(kt + 2, 1);
    BARRIER; WAITL0;
    PHASE_MFMA(4)
    BARRIER;

    // phase 3: A m6,m7; stage A(kt+2)q2; counted end-of-tile wait
    PHASE_READ_A(6)
    if (kt + 2 < NKT) stageAq(kt + 2, 2);
    if (kt + 1 < NKT) {
      if (kt + 2 < NKT) { asm volatile("s_waitcnt vmcnt(3)" ::: "memory"); }
      else              { asm volatile("s_waitcnt vmcnt(0)" ::: "memory"); }
    }
    BARRIER; WAITL0;
    PHASE_MFMA(6)
    BARRIER;
  }
#undef PHASE_READ_A
#undef PHASE_MFMA

  // ---- epilogue.  C/D: col = lane&15, row = (lane>>4)*4 + reg
  if constexpr (G1) {
#pragma unroll
    for (int n = 0; n < 4; ++n) {
      int col = nt * 256 + wn * 64 + n * 16 + (lane & 15);
      float bc = biasp[col];
#pragma unroll
      for (int m = 0; m < 8; ++m) {
        int lrb = wm * 128 + m * 16 + ((lane >> 4) << 2);
#pragma unroll
        for (int rr = 0; rr < 4; ++rr) {
          int lr = lrb + rr;
          if (lr < valid) {
            float v = acc[m][n][rr] + bc;
            Hout[(size_t)(row0 + lr) * FF + col] = (bf16_t)fast_gelu(v);
          }
        }
      }
    }
  } else {
#pragma unroll
    for (int m = 0; m < 8; ++m) {
      int lrb = wm * 128 + m * 16 + ((lane >> 4) << 2);
#pragma unroll
      for (int rr = 0; rr < 4; ++rr) {
        int lr = lrb + rr;
        if (lr >= valid) continue;
#pragma unroll
        for (int n = 0; n < 4; ++n) {
          int col = nt * 256 + wn * 64 + n * 16 + (lane & 15);
          out[(size_t)(row0 + lr) * DD + col] = acc[m][n][rr] + biasp[col];
        }
      }
    }
  }
}

// ---------------------------------------------------------------- launch
extern "C" void kernel_launch(void* const* d_in, const int* in_sizes, int n_in,
                              void* d_out, int out_size, void* d_ws, size_t ws_size,
                              hipStream_t stream) {
  const float* x   = (const float*)d_in[0];
  const float* gw  = (const float*)d_in[1];
  const float* w1  = (const float*)d_in[2];
  const float* b1  = (const float*)d_in[3];
  const float* w2  = (const float*)d_in[4];
  const float* b2  = (const float*)d_in[5];
  const float* sw1 = (const float*)d_in[6];
  const float* sb1 = (const float*)d_in[7];
  const float* sw2 = (const float*)d_in[8];
  const float* sb2 = (const float*)d_in[9];
  float* out = (float*)d_out;

  char* ws = (char*)d_ws;
  bf16_t* xb    = (bf16_t*)(ws);                          // 16 MB  [dead after expert G1]
  bf16_t* w1b   = (bf16_t*)(ws + ((size_t)16 << 20));     // 64 MB  [dead after expert G1]
  bf16_t* w2b   = (bf16_t*)(ws + ((size_t)80 << 20));     // 64 MB
  bf16_t* sw1b  = (bf16_t*)(ws + ((size_t)144 << 20));    // 8 MB
  bf16_t* sw2b  = (bf16_t*)(ws + ((size_t)152 << 20));    // 8 MB
  bf16_t* Hbuf  = (bf16_t*)(ws + ((size_t)160 << 20));    // 128 MB (16384 x 4096 bf16)
  float*  slotbuf = (float*)(ws);                         // 67 MB, overlaps xb+w1b (dead by then)
  float*  topkw = (float*)(ws + ((size_t)288 << 20));     // 64 KB
  int*    slote = (int*)(ws + ((size_t)288 << 20) + 65536);
  int*    perm  = (int*)(ws + ((size_t)288 << 20) + 2 * 65536);
  int*    pos   = (int*)(ws + ((size_t)288 << 20) + 3 * 65536);
  int*    routing = (int*)(ws + ((size_t)288 << 20) + 4 * 65536);

  hipMemsetAsync(routing, 0, R_INTS * sizeof(int), stream);

  // fp32 -> bf16 conversions
  cvt_f32_bf16<<<(TT * DD / 8 + 255) / 256, 256, 0, stream>>>(x, xb, TT * DD / 8);
  cvt_f32_bf16<<<(8 * FF * DD / 8 + 255) / 256, 256, 0, stream>>>(w1, w1b, 8 * FF * DD / 8);
  cvt_f32_bf16<<<(8 * DD * FF / 8 + 255) / 256, 256, 0, stream>>>(w2, w2b, 8 * DD * FF / 8);
  cvt_f32_bf16<<<(FF * DD / 8 + 255) / 256, 256, 0, stream>>>(sw1, sw1b, FF * DD / 8);
  cvt_f32_bf16<<<(DD * FF / 8 + 255) / 256, 256, 0, stream>>>(sw2, sw2b, DD * FF / 8);

  // routing
  gate_kernel<<<TT / 4, 256, 0, stream>>>(x, gw, topkw, slote, routing);
  scan_kernel<<<1, 1, 0, stream>>>(routing);
  scatter_kernel<<<NSLOT / 256, 256, 0, stream>>>(slote, routing, perm, pos);

  // shared expert first (plain store covers all of out), then experts into slotbuf
  gemm_kernel<2><<<32 * 16, 512, 0, stream>>>(xb, sw1b, sb1, Hbuf, out, routing, perm);
  gemm_kernel<3><<<32 * 4, 512, 0, stream>>>(Hbuf, sw2b, sb2, nullptr, out, routing, perm);
  gemm_kernel<0><<<72 * 16, 512, 0, stream>>>(xb, w1b, b1, Hbuf, out, routing, perm);
  gemm_kernel<1><<<72 * 4, 512, 0, stream>>>(Hbuf, w2b, b2, nullptr, slotbuf, routing, perm);

  // out += gate-weighted expert contributions
  combine_kernel<<<TT, 256, 0, stream>>>(slotbuf, pos, topkw, out);
}

// Round 8
// 973.557 us; speedup vs baseline: 1.5300x; 1.1145x over previous
//
#include <hip/hip_runtime.h>
#include <hip/hip_bf16.h>

typedef __bf16 bf16_t;
typedef __bf16 bf16x8 __attribute__((ext_vector_type(8)));
typedef float  f32x4  __attribute__((ext_vector_type(4)));

static constexpr int TT = 8192;     // tokens (2*4096)
static constexpr int DD = 1024;
static constexpr int FF = 4096;
static constexpr int NSLOT = 2 * TT;  // 16384 (token, k) slots

// routing int-array layout
#define R_COUNTS 0
#define R_OFFSET 8
#define R_TSTART 17
#define R_CURSOR 26
#define R_TOTAL  34
#define R_INTS   40

#define GLL(g, l) __builtin_amdgcn_global_load_lds( \
    (__attribute__((address_space(1))) void*)(g), \
    (__attribute__((address_space(3))) void*)(l), 16, 0, 0)

__device__ __forceinline__ float fast_gelu(float v) {
  float t = -1.5957691216f * v - 0.0713548162f * (v * v * v);
  return v / (1.f + __expf(t));
}

// ---------------------------------------------------------------- convert
__global__ __launch_bounds__(256) void cvt_f32_bf16(const float* __restrict__ src,
                                                    bf16_t* __restrict__ dst, int n8) {
  int i = blockIdx.x * 256 + threadIdx.x;
  if (i >= n8) return;
  const float4* s = reinterpret_cast<const float4*>(src) + (size_t)i * 2;
  float4 a = s[0], b = s[1];
  bf16x8 v;
  v[0] = (bf16_t)a.x; v[1] = (bf16_t)a.y; v[2] = (bf16_t)a.z; v[3] = (bf16_t)a.w;
  v[4] = (bf16_t)b.x; v[5] = (bf16_t)b.y; v[6] = (bf16_t)b.z; v[7] = (bf16_t)b.w;
  *reinterpret_cast<bf16x8*>(dst + (size_t)i * 8) = v;
}

// ---------------------------------------------------------------- gate
__global__ __launch_bounds__(256) void gate_kernel(const float* __restrict__ x,
                                                   const float* __restrict__ gw,
                                                   float* __restrict__ topkw,
                                                   int* __restrict__ slote,
                                                   int* __restrict__ routing) {
  int wid = threadIdx.x >> 6, lane = threadIdx.x & 63;
  int t = blockIdx.x * 4 + wid;
  const float4* xv = reinterpret_cast<const float4*>(x + (size_t)t * DD) + lane * 4;
  const float4* gv = reinterpret_cast<const float4*>(gw);
  float acc[8];
#pragma unroll
  for (int e = 0; e < 8; ++e) acc[e] = 0.f;
#pragma unroll
  for (int i = 0; i < 4; ++i) {
    float4 xi = xv[i];
#pragma unroll
    for (int e = 0; e < 8; ++e) {
      float4 g = gv[e * 256 + lane * 4 + i];
      acc[e] += xi.x * g.x + xi.y * g.y + xi.z * g.z + xi.w * g.w;
    }
  }
#pragma unroll
  for (int e = 0; e < 8; ++e)
    for (int off = 32; off; off >>= 1) acc[e] += __shfl_xor(acc[e], off, 64);
  if (lane == 0) {
    float m = acc[0];
#pragma unroll
    for (int e = 1; e < 8; ++e) m = fmaxf(m, acc[e]);
    float p[8], s = 0.f;
#pragma unroll
    for (int e = 0; e < 8; ++e) { p[e] = expf(acc[e] - m); s += p[e]; }
    float inv = 1.f / s;
#pragma unroll
    for (int e = 0; e < 8; ++e) p[e] *= inv;
    int e1 = 0; float b1v = p[0];
#pragma unroll
    for (int e = 1; e < 8; ++e) if (p[e] > b1v) { b1v = p[e]; e1 = e; }
    int e2 = -1; float b2v = -1.f;
#pragma unroll
    for (int e = 0; e < 8; ++e) if (e != e1 && p[e] > b2v) { b2v = p[e]; e2 = e; }
    topkw[2 * t] = b1v;  topkw[2 * t + 1] = b2v;
    slote[2 * t] = e1;   slote[2 * t + 1] = e2;
    atomicAdd(&routing[R_COUNTS + e1], 1);
    atomicAdd(&routing[R_COUNTS + e2], 1);
  }
}

// ---------------------------------------------------------------- scan (1 thread)
__global__ void scan_kernel(int* __restrict__ routing) {
  int off = 0, tt = 0;
  for (int e = 0; e < 8; ++e) {
    routing[R_OFFSET + e] = off;
    routing[R_TSTART + e] = tt;
    int c = routing[R_COUNTS + e];
    off += c;
    tt += (c + 255) >> 8;   // 256-row M-tiles
    routing[R_CURSOR + e] = 0;
  }
  routing[R_OFFSET + 8] = off;
  routing[R_TSTART + 8] = tt;
  routing[R_TOTAL] = tt;
}

// ---------------------------------------------------------------- scatter
__global__ __launch_bounds__(256) void scatter_kernel(const int* __restrict__ slote,
                                                      int* __restrict__ routing,
                                                      int* __restrict__ perm,
                                                      int* __restrict__ pos) {
  int s = blockIdx.x * 256 + threadIdx.x;
  int e = slote[s];
  int p = atomicAdd(&routing[R_CURSOR + e], 1);
  int pp = routing[R_OFFSET + e] + p;
  perm[pp] = s;
  pos[s] = pp;
}

// ---------------------------------------------------------------- combine
__global__ __launch_bounds__(256) void combine_kernel(const float* __restrict__ slotbuf,
                                                      const int* __restrict__ pos,
                                                      const float* __restrict__ topkw,
                                                      float* __restrict__ out) {
  int idx = blockIdx.x * 256 + threadIdx.x;   // one float4 per thread
  int t = idx >> 8;                            // DD/4 = 256 float4 per token
  int c = (idx & 255) << 2;
  int p0 = pos[2 * t], p1 = pos[2 * t + 1];
  float w0 = topkw[2 * t], w1 = topkw[2 * t + 1];
  float4 o = *reinterpret_cast<const float4*>(&out[(size_t)t * DD + c]);
  float4 s0 = *reinterpret_cast<const float4*>(&slotbuf[(size_t)p0 * DD + c]);
  float4 s1 = *reinterpret_cast<const float4*>(&slotbuf[(size_t)p1 * DD + c]);
  o.x += w0 * s0.x + w1 * s1.x;
  o.y += w0 * s0.y + w1 * s1.y;
  o.z += w0 * s0.z + w1 * s1.z;
  o.w += w0 * s0.w + w1 * s1.w;
  *reinterpret_cast<float4*>(&out[(size_t)t * DD + c]) = o;
}

// ---------------------------------------------------------------- GEMM
// 256x128 tile, BK=32, double-buffered (48 KB LDS), 8 waves, per-wave 64x64,
// __launch_bounds__(512,4) -> target 2 blocks/CU so cross-block TLP overlaps
// LDS-read/staging windows with MFMA (m114 mechanism). Simple proven m97 loop:
// STAGE(next buf) -> ds_read(cur) -> MFMA -> __syncthreads (vmcnt+lgkm drain).
//
// LDS swizzle (64 B row = 4 chunks of 16 B): phys_chunk = log_chunk ^ ((row>>1)&3),
// applied both sides (pre-swizzled global source + swizzled read) -> 2-way max = free.
//
// MODE 0: expert G1 (A gathered via perm, K=1024) -> fast_gelu -> H (bf16)
// MODE 1: expert G2 (A = H rows, K=4096)          -> (.+b2) store slotbuf fp32
// MODE 2: shared G1 (A = x direct, K=1024)        -> fast_gelu -> H (bf16)
// MODE 3: shared G2 (A = H rows, K=4096)          -> plain store out (+sb2)
template <int MODE>
__global__ __launch_bounds__(512, 4) void gemm_kernel(
    const bf16_t* __restrict__ A, const bf16_t* __restrict__ Bw,
    const float* __restrict__ bias, bf16_t* __restrict__ Hout,
    float* __restrict__ out, const int* __restrict__ routing,
    const int* __restrict__ perm) {
  constexpr bool G1 = (MODE == 0 || MODE == 2);
  constexpr bool EXPERT = (MODE < 2);
  constexpr int K = G1 ? 1024 : 4096;
  constexpr int NTOT = G1 ? 4096 : 1024;
  constexpr int NT = NTOT / 128;   // 32 or 8 (pow2)
  constexpr int NKT = K / 32;      // 32 or 128
  constexpr int OUTD = G1 ? FF : DD;

  // buffer: A 256x32 (8192 el) + B 128x32 (4096 el) = 12288 el = 24 KB; x2 = 48 KB
  __shared__ __align__(16) bf16_t lds[2 * 12288];

  const int t = threadIdx.x;
  const int lane = t & 63;
  const int wid = t >> 6;          // 0..7
  const int wm = wid >> 1;         // 0..3  (64-row block)
  const int wn = wid & 1;          // 0..1  (64-col half)

  // ---- block decode: bijective XCD swizzle, nt-fastest (A-panel L2 reuse)
  const int nwg = gridDim.x;
  const int q = nwg >> 3, r = nwg & 7;
  const int xcd = blockIdx.x & 7, bi = blockIdx.x >> 3;
  const int swz = (xcd < r ? xcd * (q + 1) : r * (q + 1) + (xcd - r) * q) + bi;
  const int mt = swz / NT;
  const int nt = swz & (NT - 1);

  int row0, valid, eidx = 0;
  if constexpr (EXPERT) {
    if (mt >= routing[R_TOTAL]) return;
    int e = 0;
    while (e < 7 && routing[R_TSTART + e + 1] <= mt) ++e;
    eidx = e;
    int lm = mt - routing[R_TSTART + e];
    row0 = routing[R_OFFSET + e] + lm * 256;
    valid = min(256, routing[R_COUNTS + e] - lm * 256);
  } else {
    row0 = mt * 256;
    valid = 256;
  }

  const bf16_t* Bexp = Bw + (EXPERT ? (size_t)eidx * NTOT * K : 0);
  const float* biasp = bias + (EXPERT ? eidx * NTOT : 0);

  // ---- staging: 3 GLL/thread per K-tile (A 16 KB + B 8 KB = 24 KB)
  // thread t: row = t>>2 (phys chunk t&3); source logical chunk sc = (t&3)^((t>>3)&3)
  const int srow = t >> 2;                    // 0..127
  const int sc = (t & 3) ^ ((t >> 3) & 3);
  const bf16_t *aS0, *aS1, *bS;
  {
    int gr0, gr1;
    if constexpr (MODE == 0) {
      gr0 = perm[row0 + min(srow, valid - 1)] >> 1;
      gr1 = perm[row0 + min(128 + srow, valid - 1)] >> 1;
    } else if constexpr (MODE == 1) {
      gr0 = row0 + min(srow, valid - 1);
      gr1 = row0 + min(128 + srow, valid - 1);
    } else {
      gr0 = row0 + srow;
      gr1 = row0 + 128 + srow;
    }
    aS0 = A + (size_t)gr0 * K + sc * 8;
    aS1 = A + (size_t)gr1 * K + sc * 8;
    bS  = Bexp + (size_t)(nt * 128 + srow) * K + sc * 8;
  }
  bf16_t* const dst0 = lds + (t << 3);

  auto STAGE = [&](int j) {
    bf16_t* base = dst0 + (j & 1) * 12288;
    const size_t kof = (size_t)j * 32;
    GLL(aS0 + kof, base);
    GLL(aS1 + kof, base + 4096);
    GLL(bS + kof,  base + 8192);
  };

  // ---- fragment read offsets (elements). phys chunk = (lane>>4) ^ ((lane>>1)&3)
  const int phc = ((lane >> 4) ^ ((lane >> 1) & 3)) << 3;
  const int aBase = (wm * 64 + (lane & 15)) * 32 + phc;           // + m*512
  const int bBase = 8192 + (wn * 64 + (lane & 15)) * 32 + phc;    // + n*512

  f32x4 acc[4][4];
#pragma unroll
  for (int m = 0; m < 4; ++m)
#pragma unroll
    for (int n = 0; n < 4; ++n) acc[m][n] = f32x4{0.f, 0.f, 0.f, 0.f};

  STAGE(0);
  __syncthreads();

  for (int kt = 0; kt < NKT; ++kt) {
    if (kt + 1 < NKT) STAGE(kt + 1);
    const bf16_t* buf = lds + (kt & 1) * 12288;
    bf16x8 af[4], bfr[4];
#pragma unroll
    for (int m = 0; m < 4; ++m)
      af[m] = *reinterpret_cast<const bf16x8*>(buf + aBase + m * 512);
#pragma unroll
    for (int n = 0; n < 4; ++n)
      bfr[n] = *reinterpret_cast<const bf16x8*>(buf + bBase + n * 512);

    __builtin_amdgcn_s_setprio(1);
#pragma unroll
    for (int m = 0; m < 4; ++m)
#pragma unroll
      for (int n = 0; n < 4; ++n)
        acc[m][n] = __builtin_amdgcn_mfma_f32_16x16x32_bf16(af[m], bfr[n], acc[m][n], 0, 0, 0);
    __builtin_amdgcn_s_setprio(0);

    __syncthreads();   // drains vmcnt(0)+lgkmcnt(0): stage(kt+1) landed, reads done
  }

  // ---- epilogue via LDS transpose: coalesced vector stores, no write-amp.
  // C/D frag: col = lane&15, row = (lane>>4)*4 + rr  [m89-verified]
  const int l15 = lane & 15, lq = lane >> 4;
  float bc[4];
#pragma unroll
  for (int n = 0; n < 4; ++n) bc[n] = biasp[nt * 128 + wn * 64 + n * 16 + l15];

  if constexpr (G1) {
    bf16_t* scr = lds;   // 64 rows x 128 cols bf16 = 16 KB per m-iter
#pragma unroll
    for (int m = 0; m < 4; ++m) {
      __syncthreads();
#pragma unroll
      for (int n = 0; n < 4; ++n)
#pragma unroll
        for (int rr = 0; rr < 4; ++rr) {
          float v = acc[m][n][rr] + bc[n];
          scr[(wm * 16 + lq * 4 + rr) * 128 + wn * 64 + n * 16 + l15] = (bf16_t)fast_gelu(v);
        }
      __syncthreads();
#pragma unroll
      for (int i = 0; i < 2; ++i) {
        int c = t + i * 512;
        int rowp = c >> 4, cc = c & 15;
        int lr = (rowp >> 4) * 64 + m * 16 + (rowp & 15);
        if (lr < valid) {
          bf16x8 v8 = *reinterpret_cast<const bf16x8*>(&scr[rowp * 128 + cc * 8]);
          *reinterpret_cast<bf16x8*>(&Hout[(size_t)(row0 + lr) * OUTD + nt * 128 + cc * 8]) = v8;
        }
      }
    }
  } else {
    float* scr = reinterpret_cast<float*>(lds);   // 64 x 128 f32 = 32 KB per m-iter
#pragma unroll
    for (int m = 0; m < 4; ++m) {
      __syncthreads();
#pragma unroll
      for (int n = 0; n < 4; ++n)
#pragma unroll
        for (int rr = 0; rr < 4; ++rr)
          scr[(wm * 16 + lq * 4 + rr) * 128 + wn * 64 + n * 16 + l15] = acc[m][n][rr] + bc[n];
      __syncthreads();
#pragma unroll
      for (int i = 0; i < 4; ++i) {
        int c = t + i * 512;
        int rowp = c >> 5, cc = c & 31;
        int lr = (rowp >> 4) * 64 + m * 16 + (rowp & 15);
        if (lr < valid) {
          float4 v4 = *reinterpret_cast<const float4*>(&scr[rowp * 128 + cc * 4]);
          *reinterpret_cast<float4*>(&out[(size_t)(row0 + lr) * OUTD + nt * 128 + cc * 4]) = v4;
        }
      }
    }
  }
}

// ---------------------------------------------------------------- launch
extern "C" void kernel_launch(void* const* d_in, const int* in_sizes, int n_in,
                              void* d_out, int out_size, void* d_ws, size_t ws_size,
                              hipStream_t stream) {
  const float* x   = (const float*)d_in[0];
  const float* gw  = (const float*)d_in[1];
  const float* w1  = (const float*)d_in[2];
  const float* b1  = (const float*)d_in[3];
  const float* w2  = (const float*)d_in[4];
  const float* b2  = (const float*)d_in[5];
  const float* sw1 = (const float*)d_in[6];
  const float* sb1 = (const float*)d_in[7];
  const float* sw2 = (const float*)d_in[8];
  const float* sb2 = (const float*)d_in[9];
  float* out = (float*)d_out;

  char* ws = (char*)d_ws;
  bf16_t* xb    = (bf16_t*)(ws);                          // 16 MB  [dead after expert G1]
  bf16_t* w1b   = (bf16_t*)(ws + ((size_t)16 << 20));     // 64 MB  [dead after expert G1]
  bf16_t* w2b   = (bf16_t*)(ws + ((size_t)80 << 20));     // 64 MB
  bf16_t* sw1b  = (bf16_t*)(ws + ((size_t)144 << 20));    // 8 MB
  bf16_t* sw2b  = (bf16_t*)(ws + ((size_t)152 << 20));    // 8 MB
  bf16_t* Hbuf  = (bf16_t*)(ws + ((size_t)160 << 20));    // 128 MB (16384 x 4096 bf16)
  float*  slotbuf = (float*)(ws);                         // 67 MB, overlaps xb+w1b (dead by then)
  float*  topkw = (float*)(ws + ((size_t)288 << 20));     // 64 KB
  int*    slote = (int*)(ws + ((size_t)288 << 20) + 65536);
  int*    perm  = (int*)(ws + ((size_t)288 << 20) + 2 * 65536);
  int*    pos   = (int*)(ws + ((size_t)288 << 20) + 3 * 65536);
  int*    routing = (int*)(ws + ((size_t)288 << 20) + 4 * 65536);

  hipMemsetAsync(routing, 0, R_INTS * sizeof(int), stream);

  // fp32 -> bf16 conversions
  cvt_f32_bf16<<<(TT * DD / 8 + 255) / 256, 256, 0, stream>>>(x, xb, TT * DD / 8);
  cvt_f32_bf16<<<(8 * FF * DD / 8 + 255) / 256, 256, 0, stream>>>(w1, w1b, 8 * FF * DD / 8);
  cvt_f32_bf16<<<(8 * DD * FF / 8 + 255) / 256, 256, 0, stream>>>(w2, w2b, 8 * DD * FF / 8);
  cvt_f32_bf16<<<(FF * DD / 8 + 255) / 256, 256, 0, stream>>>(sw1, sw1b, FF * DD / 8);
  cvt_f32_bf16<<<(DD * FF / 8 + 255) / 256, 256, 0, stream>>>(sw2, sw2b, DD * FF / 8);

  // routing
  gate_kernel<<<TT / 4, 256, 0, stream>>>(x, gw, topkw, slote, routing);
  scan_kernel<<<1, 1, 0, stream>>>(routing);
  scatter_kernel<<<NSLOT / 256, 256, 0, stream>>>(slote, routing, perm, pos);

  // shared expert first (plain store covers all of out), then experts into slotbuf
  gemm_kernel<2><<<32 * 32, 512, 0, stream>>>(xb, sw1b, sb1, Hbuf, out, routing, perm);
  gemm_kernel<3><<<32 * 8, 512, 0, stream>>>(Hbuf, sw2b, sb2, nullptr, out, routing, perm);
  gemm_kernel<0><<<72 * 32, 512, 0, stream>>>(xb, w1b, b1, Hbuf, out, routing, perm);
  gemm_kernel<1><<<72 * 8, 512, 0, stream>>>(Hbuf, w2b, b2, nullptr, slotbuf, routing, perm);

  // out += gate-weighted expert contributions
  combine_kernel<<<TT, 256, 0, stream>>>(slotbuf, pos, topkw, out);
}

// Round 9
// 928.976 us; speedup vs baseline: 1.6034x; 1.0480x over previous
//
#include <hip/hip_runtime.h>
#include <hip/hip_bf16.h>

typedef __bf16 bf16_t;
typedef __bf16 bf16x8 __attribute__((ext_vector_type(8)));
typedef float  f32x4  __attribute__((ext_vector_type(4)));

static constexpr int TT = 8192;     // tokens (2*4096)
static constexpr int DD = 1024;
static constexpr int FF = 4096;
static constexpr int NSLOT = 2 * TT;  // 16384 (token, k) slots

// routing int-array layout
#define R_COUNTS 0
#define R_OFFSET 8
#define R_TSTART 17
#define R_CURSOR 26
#define R_TOTAL  34
#define R_INTS   40

#define GLL(g, l) __builtin_amdgcn_global_load_lds( \
    (__attribute__((address_space(1))) void*)(g), \
    (__attribute__((address_space(3))) void*)(l), 16, 0, 0)

__device__ __forceinline__ float fast_gelu(float v) {
  float t = -1.5957691216f * v - 0.0713548162f * (v * v * v);
  return v / (1.f + __expf(t));
}

// ---------------------------------------------------------------- convert
__global__ __launch_bounds__(256) void cvt_f32_bf16(const float* __restrict__ src,
                                                    bf16_t* __restrict__ dst, int n8) {
  int i = blockIdx.x * 256 + threadIdx.x;
  if (i >= n8) return;
  const float4* s = reinterpret_cast<const float4*>(src) + (size_t)i * 2;
  float4 a = s[0], b = s[1];
  bf16x8 v;
  v[0] = (bf16_t)a.x; v[1] = (bf16_t)a.y; v[2] = (bf16_t)a.z; v[3] = (bf16_t)a.w;
  v[4] = (bf16_t)b.x; v[5] = (bf16_t)b.y; v[6] = (bf16_t)b.z; v[7] = (bf16_t)b.w;
  *reinterpret_cast<bf16x8*>(dst + (size_t)i * 8) = v;
}

// ---------------------------------------------------------------- gate
__global__ __launch_bounds__(256) void gate_kernel(const float* __restrict__ x,
                                                   const float* __restrict__ gw,
                                                   float* __restrict__ topkw,
                                                   int* __restrict__ slote,
                                                   int* __restrict__ routing) {
  int wid = threadIdx.x >> 6, lane = threadIdx.x & 63;
  int t = blockIdx.x * 4 + wid;
  const float4* xv = reinterpret_cast<const float4*>(x + (size_t)t * DD) + lane * 4;
  const float4* gv = reinterpret_cast<const float4*>(gw);
  float acc[8];
#pragma unroll
  for (int e = 0; e < 8; ++e) acc[e] = 0.f;
#pragma unroll
  for (int i = 0; i < 4; ++i) {
    float4 xi = xv[i];
#pragma unroll
    for (int e = 0; e < 8; ++e) {
      float4 g = gv[e * 256 + lane * 4 + i];
      acc[e] += xi.x * g.x + xi.y * g.y + xi.z * g.z + xi.w * g.w;
    }
  }
#pragma unroll
  for (int e = 0; e < 8; ++e)
    for (int off = 32; off; off >>= 1) acc[e] += __shfl_xor(acc[e], off, 64);
  if (lane == 0) {
    float m = acc[0];
#pragma unroll
    for (int e = 1; e < 8; ++e) m = fmaxf(m, acc[e]);
    float p[8], s = 0.f;
#pragma unroll
    for (int e = 0; e < 8; ++e) { p[e] = expf(acc[e] - m); s += p[e]; }
    float inv = 1.f / s;
#pragma unroll
    for (int e = 0; e < 8; ++e) p[e] *= inv;
    int e1 = 0; float b1v = p[0];
#pragma unroll
    for (int e = 1; e < 8; ++e) if (p[e] > b1v) { b1v = p[e]; e1 = e; }
    int e2 = -1; float b2v = -1.f;
#pragma unroll
    for (int e = 0; e < 8; ++e) if (e != e1 && p[e] > b2v) { b2v = p[e]; e2 = e; }
    topkw[2 * t] = b1v;  topkw[2 * t + 1] = b2v;
    slote[2 * t] = e1;   slote[2 * t + 1] = e2;
    atomicAdd(&routing[R_COUNTS + e1], 1);
    atomicAdd(&routing[R_COUNTS + e2], 1);
  }
}

// ---------------------------------------------------------------- scan (1 thread)
__global__ void scan_kernel(int* __restrict__ routing) {
  int off = 0, tt = 0;
  for (int e = 0; e < 8; ++e) {
    routing[R_OFFSET + e] = off;
    routing[R_TSTART + e] = tt;
    int c = routing[R_COUNTS + e];
    off += c;
    tt += (c + 127) >> 7;   // 128-row M-tiles
    routing[R_CURSOR + e] = 0;
  }
  routing[R_OFFSET + 8] = off;
  routing[R_TSTART + 8] = tt;
  routing[R_TOTAL] = tt;
}

// ---------------------------------------------------------------- scatter
__global__ __launch_bounds__(256) void scatter_kernel(const int* __restrict__ slote,
                                                      int* __restrict__ routing,
                                                      int* __restrict__ perm,
                                                      int* __restrict__ pos) {
  int s = blockIdx.x * 256 + threadIdx.x;
  int e = slote[s];
  int p = atomicAdd(&routing[R_CURSOR + e], 1);
  int pp = routing[R_OFFSET + e] + p;
  perm[pp] = s;
  pos[s] = pp;
}

// ---------------------------------------------------------------- combine
__global__ __launch_bounds__(256) void combine_kernel(const float* __restrict__ slotbuf,
                                                      const int* __restrict__ pos,
                                                      const float* __restrict__ topkw,
                                                      float* __restrict__ out) {
  int idx = blockIdx.x * 256 + threadIdx.x;   // one float4 per thread
  int t = idx >> 8;                            // DD/4 = 256 float4 per token
  int c = (idx & 255) << 2;
  int p0 = pos[2 * t], p1 = pos[2 * t + 1];
  float w0 = topkw[2 * t], w1 = topkw[2 * t + 1];
  float4 o = *reinterpret_cast<const float4*>(&out[(size_t)t * DD + c]);
  float4 s0 = *reinterpret_cast<const float4*>(&slotbuf[(size_t)p0 * DD + c]);
  float4 s1 = *reinterpret_cast<const float4*>(&slotbuf[(size_t)p1 * DD + c]);
  o.x += w0 * s0.x + w1 * s1.x;
  o.y += w0 * s0.y + w1 * s1.y;
  o.z += w0 * s0.z + w1 * s1.z;
  o.w += w0 * s0.w + w1 * s1.w;
  *reinterpret_cast<float4*>(&out[(size_t)t * DD + c]) = o;
}

// ---------------------------------------------------------------- GEMM (m97 replica)
// 128x128 tile, BK=64, 256 threads / 4 waves (2x2), per-wave 64x64 (4x4 frags),
// SINGLE 32 KB LDS buffer, loop = {STAGE(kt); sync; ds_read+MFMA; sync}.
// 32 KB LDS + ~124 regs -> 4 blocks/CU: cross-block TLP covers the staging drain
// (m114 mechanism; m97 measured 912 TF with 3 blocks/CU).
//
// Row = 128 B = 8 chunks of 16 B; swizzle phys_chunk = log_chunk ^ (row&7),
// applied BOTH sides (pre-swizzled global source + swizzled ds_read) -> 2-way max.
//
// MODE 0: expert G1 (A gathered via perm, K=1024) -> fast_gelu -> H (bf16)
// MODE 1: expert G2 (A = H rows, K=4096)          -> (.+b2) store slotbuf fp32
// MODE 2: shared G1 (A = x direct, K=1024)        -> fast_gelu -> H (bf16)
// MODE 3: shared G2 (A = H rows, K=4096)          -> plain store out (+sb2)
template <int MODE>
__global__ __launch_bounds__(256, 4) void gemm_kernel(
    const bf16_t* __restrict__ A, const bf16_t* __restrict__ Bw,
    const float* __restrict__ bias, bf16_t* __restrict__ Hout,
    float* __restrict__ out, const int* __restrict__ routing,
    const int* __restrict__ perm) {
  constexpr bool G1 = (MODE == 0 || MODE == 2);
  constexpr bool EXPERT = (MODE < 2);
  constexpr int K = G1 ? 1024 : 4096;
  constexpr int NTOT = G1 ? 4096 : 1024;
  constexpr int NT = NTOT / 128;   // 32 or 8 (pow2)
  constexpr int NKT = K / 64;      // 16 or 64
  constexpr int OUTD = G1 ? FF : DD;

  // single buffer: A 128x64 + B 128x64 bf16 = 32 KB
  __shared__ __align__(16) bf16_t lds[16384];

  const int t = threadIdx.x;
  const int lane = t & 63;
  const int wid = t >> 6;          // 0..3
  const int wm = wid >> 1;         // 0..1
  const int wn = wid & 1;          // 0..1

  // ---- block decode: bijective XCD swizzle, nt-fastest (A-panel L2 reuse)
  const int nwg = gridDim.x;
  const int q = nwg >> 3, r = nwg & 7;
  const int xcd = blockIdx.x & 7, bi = blockIdx.x >> 3;
  const int swz = (xcd < r ? xcd * (q + 1) : r * (q + 1) + (xcd - r) * q) + bi;
  const int mt = swz / NT;
  const int nt = swz & (NT - 1);

  int row0, valid, eidx = 0;
  if constexpr (EXPERT) {
    if (mt >= routing[R_TOTAL]) return;
    int e = 0;
    while (e < 7 && routing[R_TSTART + e + 1] <= mt) ++e;
    eidx = e;
    int lm = mt - routing[R_TSTART + e];
    row0 = routing[R_OFFSET + e] + lm * 128;
    valid = min(128, routing[R_COUNTS + e] - lm * 128);
  } else {
    row0 = mt * 128;
    valid = 128;
  }

  const bf16_t* Bexp = Bw + (EXPERT ? (size_t)eidx * NTOT * K : 0);
  const float* biasp = bias + (EXPERT ? eidx * NTOT : 0);

  // ---- staging: 8 GLL/thread per K-tile (A 16 KB + B 16 KB)
  // thread t: rows sub+32i (sub = t>>3), phys chunk t&7;
  // source logical chunk = (t&7) ^ (row&7) = (t&7) ^ (sub&7)   [32 ≡ 0 mod 8]
  const int sub = t >> 3;                     // 0..31
  const int lc = (t & 7) ^ (sub & 7);
  const bf16_t* aS[4];
  const bf16_t* bS[4];
#pragma unroll
  for (int i = 0; i < 4; ++i) {
    int lr = sub + i * 32;                    // 0..127
    int gr;
    if constexpr (MODE == 0) {
      gr = perm[row0 + min(lr, valid - 1)] >> 1;
    } else if constexpr (MODE == 1) {
      gr = row0 + min(lr, valid - 1);
    } else {
      gr = row0 + lr;
    }
    aS[i] = A + (size_t)gr * K + lc * 8;
    bS[i] = Bexp + (size_t)(nt * 128 + lr) * K + lc * 8;
  }
  // LDS dest (elements): row*64 + (t&7)*8 ; B at +8192
  bf16_t* const aD = lds + (sub << 6) + ((t & 7) << 3);
  bf16_t* const bD = aD + 8192;

  // ---- fragment read offsets: logical chunk ck = kk*4 + (lane>>4); phys = ck^(row&7)
  const int l15 = lane & 15, lq = lane >> 4;

  f32x4 acc[4][4];
#pragma unroll
  for (int m = 0; m < 4; ++m)
#pragma unroll
    for (int n = 0; n < 4; ++n) acc[m][n] = f32x4{0.f, 0.f, 0.f, 0.f};

  for (int kt = 0; kt < NKT; ++kt) {
    const size_t kof = (size_t)kt * 64;
#pragma unroll
    for (int i = 0; i < 4; ++i) {
      GLL(aS[i] + kof, aD + i * 2048);
      GLL(bS[i] + kof, bD + i * 2048);
    }
    __syncthreads();   // drains vmcnt: tile kt fully in LDS

#pragma unroll
    for (int kk = 0; kk < 2; ++kk) {
      bf16x8 af[4], bfr[4];
#pragma unroll
      for (int m = 0; m < 4; ++m) {
        int ra = wm * 64 + m * 16 + l15;
        int ph = (kk * 4 + lq) ^ (ra & 7);
        af[m] = *reinterpret_cast<const bf16x8*>(&lds[ra * 64 + ph * 8]);
      }
#pragma unroll
      for (int n = 0; n < 4; ++n) {
        int rb = wn * 64 + n * 16 + l15;
        int ph = (kk * 4 + lq) ^ (rb & 7);
        bfr[n] = *reinterpret_cast<const bf16x8*>(&lds[8192 + rb * 64 + ph * 8]);
      }
      __builtin_amdgcn_s_setprio(1);
#pragma unroll
      for (int m = 0; m < 4; ++m)
#pragma unroll
        for (int n = 0; n < 4; ++n)
          acc[m][n] = __builtin_amdgcn_mfma_f32_16x16x32_bf16(af[m], bfr[n], acc[m][n], 0, 0, 0);
      __builtin_amdgcn_s_setprio(0);
    }
    __syncthreads();   // all reads done before next STAGE overwrites
  }

  // ---- epilogue via LDS transpose: coalesced vector stores.
  // C/D frag: col = lane&15, row = (lane>>4)*4 + rr  [m89-verified]
  float bc[4];
#pragma unroll
  for (int n = 0; n < 4; ++n) bc[n] = biasp[nt * 128 + wn * 64 + n * 16 + l15];

  if constexpr (G1) {
    bf16_t* scr = lds;   // 64 x 128 bf16 = 16 KB per half
#pragma unroll
    for (int h = 0; h < 2; ++h) {
      __syncthreads();
      if (wm == h) {
#pragma unroll
        for (int m = 0; m < 4; ++m)
#pragma unroll
          for (int n = 0; n < 4; ++n)
#pragma unroll
            for (int rr = 0; rr < 4; ++rr) {
              float v = acc[m][n][rr] + bc[n];
              scr[(m * 16 + lq * 4 + rr) * 128 + wn * 64 + n * 16 + l15] = (bf16_t)fast_gelu(v);
            }
      }
      __syncthreads();
#pragma unroll
      for (int i = 0; i < 4; ++i) {
        int c = t + i * 256;                 // 0..1023 bf16x8 chunks
        int rowp = c >> 4, cc = c & 15;
        int lr = h * 64 + rowp;
        if (lr < valid) {
          bf16x8 v8 = *reinterpret_cast<const bf16x8*>(&scr[rowp * 128 + cc * 8]);
          *reinterpret_cast<bf16x8*>(&Hout[(size_t)(row0 + lr) * OUTD + nt * 128 + cc * 8]) = v8;
        }
      }
    }
  } else {
    float* scr = reinterpret_cast<float*>(lds);   // 64 x 128 f32 = 32 KB per half
#pragma unroll
    for (int h = 0; h < 2; ++h) {
      __syncthreads();
      if (wm == h) {
#pragma unroll
        for (int m = 0; m < 4; ++m)
#pragma unroll
          for (int n = 0; n < 4; ++n)
#pragma unroll
            for (int rr = 0; rr < 4; ++rr)
              scr[(m * 16 + lq * 4 + rr) * 128 + wn * 64 + n * 16 + l15] = acc[m][n][rr] + bc[n];
      }
      __syncthreads();
#pragma unroll
      for (int i = 0; i < 8; ++i) {
        int c = t + i * 256;                 // 0..2047 float4 chunks
        int rowp = c >> 5, cc = c & 31;
        int lr = h * 64 + rowp;
        if (lr < valid) {
          float4 v4 = *reinterpret_cast<const float4*>(&scr[rowp * 128 + cc * 4]);
          *reinterpret_cast<float4*>(&out[(size_t)(row0 + lr) * OUTD + nt * 128 + cc * 4]) = v4;
        }
      }
    }
  }
}

// ---------------------------------------------------------------- launch
extern "C" void kernel_launch(void* const* d_in, const int* in_sizes, int n_in,
                              void* d_out, int out_size, void* d_ws, size_t ws_size,
                              hipStream_t stream) {
  const float* x   = (const float*)d_in[0];
  const float* gw  = (const float*)d_in[1];
  const float* w1  = (const float*)d_in[2];
  const float* b1  = (const float*)d_in[3];
  const float* w2  = (const float*)d_in[4];
  const float* b2  = (const float*)d_in[5];
  const float* sw1 = (const float*)d_in[6];
  const float* sb1 = (const float*)d_in[7];
  const float* sw2 = (const float*)d_in[8];
  const float* sb2 = (const float*)d_in[9];
  float* out = (float*)d_out;

  char* ws = (char*)d_ws;
  bf16_t* xb    = (bf16_t*)(ws);                          // 16 MB  [dead after expert G1]
  bf16_t* w1b   = (bf16_t*)(ws + ((size_t)16 << 20));     // 64 MB  [dead after expert G1]
  bf16_t* w2b   = (bf16_t*)(ws + ((size_t)80 << 20));     // 64 MB
  bf16_t* sw1b  = (bf16_t*)(ws + ((size_t)144 << 20));    // 8 MB
  bf16_t* sw2b  = (bf16_t*)(ws + ((size_t)152 << 20));    // 8 MB
  bf16_t* Hbuf  = (bf16_t*)(ws + ((size_t)160 << 20));    // 128 MB (16384 x 4096 bf16)
  float*  slotbuf = (float*)(ws);                         // 67 MB, overlaps xb+w1b (dead by then)
  float*  topkw = (float*)(ws + ((size_t)288 << 20));     // 64 KB
  int*    slote = (int*)(ws + ((size_t)288 << 20) + 65536);
  int*    perm  = (int*)(ws + ((size_t)288 << 20) + 2 * 65536);
  int*    pos   = (int*)(ws + ((size_t)288 << 20) + 3 * 65536);
  int*    routing = (int*)(ws + ((size_t)288 << 20) + 4 * 65536);

  hipMemsetAsync(routing, 0, R_INTS * sizeof(int), stream);

  // fp32 -> bf16 conversions
  cvt_f32_bf16<<<(TT * DD / 8 + 255) / 256, 256, 0, stream>>>(x, xb, TT * DD / 8);
  cvt_f32_bf16<<<(8 * FF * DD / 8 + 255) / 256, 256, 0, stream>>>(w1, w1b, 8 * FF * DD / 8);
  cvt_f32_bf16<<<(8 * DD * FF / 8 + 255) / 256, 256, 0, stream>>>(w2, w2b, 8 * DD * FF / 8);
  cvt_f32_bf16<<<(FF * DD / 8 + 255) / 256, 256, 0, stream>>>(sw1, sw1b, FF * DD / 8);
  cvt_f32_bf16<<<(DD * FF / 8 + 255) / 256, 256, 0, stream>>>(sw2, sw2b, DD * FF / 8);

  // routing
  gate_kernel<<<TT / 4, 256, 0, stream>>>(x, gw, topkw, slote, routing);
  scan_kernel<<<1, 1, 0, stream>>>(routing);
  scatter_kernel<<<NSLOT / 256, 256, 0, stream>>>(slote, routing, perm, pos);

  // shared expert first (plain store covers all of out), then experts into slotbuf
  gemm_kernel<2><<<64 * 32, 256, 0, stream>>>(xb, sw1b, sb1, Hbuf, out, routing, perm);
  gemm_kernel<3><<<64 * 8, 256, 0, stream>>>(Hbuf, sw2b, sb2, nullptr, out, routing, perm);
  gemm_kernel<0><<<136 * 32, 256, 0, stream>>>(xb, w1b, b1, Hbuf, out, routing, perm);
  gemm_kernel<1><<<136 * 8, 256, 0, stream>>>(Hbuf, w2b, b2, nullptr, slotbuf, routing, perm);

  // out += gate-weighted expert contributions
  combine_kernel<<<TT, 256, 0, stream>>>(slotbuf, pos, topkw, out);
}

// Round 10
// 709.798 us; speedup vs baseline: 2.0985x; 1.3088x over previous
//
#include <hip/hip_runtime.h>
#include <hip/hip_bf16.h>

typedef __bf16 bf16_t;
typedef __bf16 bf16x8 __attribute__((ext_vector_type(8)));
typedef float  f32x4  __attribute__((ext_vector_type(4)));

static constexpr int TT = 8192;     // tokens (2*4096)
static constexpr int DD = 1024;
static constexpr int FF = 4096;
static constexpr int NSLOT = 2 * TT;  // 16384 (token, k) slots

// routing int-array layout
#define R_COUNTS 0
#define R_OFFSET 8
#define R_TSTART 17
#define R_TOTAL  34
#define R_INTS   40

#define GLL(g, l) __builtin_amdgcn_global_load_lds( \
    (__attribute__((address_space(1))) void*)(g), \
    (__attribute__((address_space(3))) void*)(l), 16, 0, 0)

__device__ __forceinline__ float fast_gelu(float v) {
  float t = -1.5957691216f * v - 0.0713548162f * (v * v * v);
  return v / (1.f + __expf(t));
}

// ---------------------------------------------------------------- convert
__global__ __launch_bounds__(256) void cvt_f32_bf16(const float* __restrict__ src,
                                                    bf16_t* __restrict__ dst, int n8) {
  int i = blockIdx.x * 256 + threadIdx.x;
  if (i >= n8) return;
  const float4* s = reinterpret_cast<const float4*>(src) + (size_t)i * 2;
  float4 a = s[0], b = s[1];
  bf16x8 v;
  v[0] = (bf16_t)a.x; v[1] = (bf16_t)a.y; v[2] = (bf16_t)a.z; v[3] = (bf16_t)a.w;
  v[4] = (bf16_t)b.x; v[5] = (bf16_t)b.y; v[6] = (bf16_t)b.z; v[7] = (bf16_t)b.w;
  *reinterpret_cast<bf16x8*>(dst + (size_t)i * 8) = v;
}

// ---------------------------------------------------------------- gate (no atomics)
__global__ __launch_bounds__(256) void gate_kernel(const float* __restrict__ x,
                                                   const float* __restrict__ gw,
                                                   float* __restrict__ topkw,
                                                   int* __restrict__ slote) {
  int wid = threadIdx.x >> 6, lane = threadIdx.x & 63;
  int t = blockIdx.x * 4 + wid;
  const float4* xv = reinterpret_cast<const float4*>(x + (size_t)t * DD) + lane * 4;
  const float4* gv = reinterpret_cast<const float4*>(gw);
  float acc[8];
#pragma unroll
  for (int e = 0; e < 8; ++e) acc[e] = 0.f;
#pragma unroll
  for (int i = 0; i < 4; ++i) {
    float4 xi = xv[i];
#pragma unroll
    for (int e = 0; e < 8; ++e) {
      float4 g = gv[e * 256 + lane * 4 + i];
      acc[e] += xi.x * g.x + xi.y * g.y + xi.z * g.z + xi.w * g.w;
    }
  }
#pragma unroll
  for (int e = 0; e < 8; ++e)
    for (int off = 32; off; off >>= 1) acc[e] += __shfl_xor(acc[e], off, 64);
  if (lane == 0) {
    float m = acc[0];
#pragma unroll
    for (int e = 1; e < 8; ++e) m = fmaxf(m, acc[e]);
    float p[8], s = 0.f;
#pragma unroll
    for (int e = 0; e < 8; ++e) { p[e] = expf(acc[e] - m); s += p[e]; }
    float inv = 1.f / s;
#pragma unroll
    for (int e = 0; e < 8; ++e) p[e] *= inv;
    int e1 = 0; float b1v = p[0];
#pragma unroll
    for (int e = 1; e < 8; ++e) if (p[e] > b1v) { b1v = p[e]; e1 = e; }
    int e2 = -1; float b2v = -1.f;
#pragma unroll
    for (int e = 0; e < 8; ++e) if (e != e1 && p[e] > b2v) { b2v = p[e]; e2 = e; }
    topkw[2 * t] = b1v;  topkw[2 * t + 1] = b2v;
    slote[2 * t] = e1;   slote[2 * t + 1] = e2;
  }
}

// ---------------------------------------------------------------- histogram (8 blocks, no atomics)
__global__ __launch_bounds__(256) void hist_kernel(const int* __restrict__ slote,
                                                   int* __restrict__ routing) {
  __shared__ int red[256];
  const int e = blockIdx.x;
  const int t = threadIdx.x;
  int cnt = 0;
  for (int base = 0; base < NSLOT; base += 256)
    cnt += (slote[base + t] == e) ? 1 : 0;
  red[t] = cnt;
  __syncthreads();
  for (int s = 128; s; s >>= 1) {
    if (t < s) red[t] += red[t + s];
    __syncthreads();
  }
  if (t == 0) routing[R_COUNTS + e] = red[0];
}

// ---------------------------------------------------------------- scan (1 thread)
__global__ void scan_kernel(int* __restrict__ routing) {
  int off = 0, tt = 0;
  for (int e = 0; e < 8; ++e) {
    routing[R_OFFSET + e] = off;
    routing[R_TSTART + e] = tt;
    int c = routing[R_COUNTS + e];
    off += c;
    tt += (c + 127) >> 7;   // 128-row M-tiles
  }
  routing[R_OFFSET + 8] = off;
  routing[R_TSTART + 8] = tt;
  routing[R_TOTAL] = tt;
}

// ---------------------------------------------------------------- scatter (8 blocks, stable, no atomics)
__global__ __launch_bounds__(256) void scatter_kernel(const int* __restrict__ slote,
                                                      const int* __restrict__ routing,
                                                      int* __restrict__ perm,
                                                      int* __restrict__ pos) {
  __shared__ int wtot[4];
  const int e = blockIdx.x;
  const int t = threadIdx.x;
  const int lane = t & 63, wid = t >> 6;
  int running = routing[R_OFFSET + e];
  for (int base = 0; base < NSLOT; base += 256) {
    int s = base + t;
    bool m = (slote[s] == e);
    unsigned long long mask = __ballot(m);
    int wrank = __popcll(mask & ((1ull << lane) - 1ull));
    if (lane == 0) wtot[wid] = __popcll(mask);
    __syncthreads();
    int wpre = 0;
#pragma unroll
    for (int w = 0; w < 4; ++w) if (w < wid) wpre += wtot[w];
    int tot = wtot[0] + wtot[1] + wtot[2] + wtot[3];
    if (m) {
      int pp = running + wpre + wrank;
      perm[pp] = s;
      pos[s] = pp;
    }
    running += tot;
    __syncthreads();
  }
}

// ---------------------------------------------------------------- combine
__global__ __launch_bounds__(256) void combine_kernel(const float* __restrict__ slotbuf,
                                                      const int* __restrict__ pos,
                                                      const float* __restrict__ topkw,
                                                      float* __restrict__ out) {
  int idx = blockIdx.x * 256 + threadIdx.x;   // one float4 per thread
  int t = idx >> 8;                            // DD/4 = 256 float4 per token
  int c = (idx & 255) << 2;
  int p0 = pos[2 * t], p1 = pos[2 * t + 1];
  float w0 = topkw[2 * t], w1 = topkw[2 * t + 1];
  float4 o = *reinterpret_cast<const float4*>(&out[(size_t)t * DD + c]);
  float4 s0 = *reinterpret_cast<const float4*>(&slotbuf[(size_t)p0 * DD + c]);
  float4 s1 = *reinterpret_cast<const float4*>(&slotbuf[(size_t)p1 * DD + c]);
  o.x += w0 * s0.x + w1 * s1.x;
  o.y += w0 * s0.y + w1 * s1.y;
  o.z += w0 * s0.z + w1 * s1.z;
  o.w += w0 * s0.w + w1 * s1.w;
  *reinterpret_cast<float4*>(&out[(size_t)t * DD + c]) = o;
}

// ---------------------------------------------------------------- GEMM (m97 replica; unchanged from R9)
// 128x128 tile, BK=64, 256 threads / 4 waves (2x2), per-wave 64x64 (4x4 frags),
// SINGLE 32 KB LDS buffer, loop = {STAGE(kt); sync; ds_read+MFMA; sync}; 4 blocks/CU.
// Row = 128 B = 8 chunks of 16 B; swizzle phys_chunk = log_chunk ^ (row&7), both sides.
// MODE 0: expert G1 (A gathered via perm, K=1024) -> fast_gelu -> H (bf16)
// MODE 1: expert G2 (A = H rows, K=4096)          -> (.+b2) store slotbuf fp32
// MODE 2: shared G1 (A = x direct, K=1024)        -> fast_gelu -> H (bf16)
// MODE 3: shared G2 (A = H rows, K=4096)          -> plain store out (+sb2)
template <int MODE>
__global__ __launch_bounds__(256, 4) void gemm_kernel(
    const bf16_t* __restrict__ A, const bf16_t* __restrict__ Bw,
    const float* __restrict__ bias, bf16_t* __restrict__ Hout,
    float* __restrict__ out, const int* __restrict__ routing,
    const int* __restrict__ perm) {
  constexpr bool G1 = (MODE == 0 || MODE == 2);
  constexpr bool EXPERT = (MODE < 2);
  constexpr int K = G1 ? 1024 : 4096;
  constexpr int NTOT = G1 ? 4096 : 1024;
  constexpr int NT = NTOT / 128;   // 32 or 8 (pow2)
  constexpr int NKT = K / 64;      // 16 or 64
  constexpr int OUTD = G1 ? FF : DD;

  __shared__ __align__(16) bf16_t lds[16384];

  const int t = threadIdx.x;
  const int lane = t & 63;
  const int wid = t >> 6;          // 0..3
  const int wm = wid >> 1;         // 0..1
  const int wn = wid & 1;          // 0..1

  const int nwg = gridDim.x;
  const int q = nwg >> 3, r = nwg & 7;
  const int xcd = blockIdx.x & 7, bi = blockIdx.x >> 3;
  const int swz = (xcd < r ? xcd * (q + 1) : r * (q + 1) + (xcd - r) * q) + bi;
  const int mt = swz / NT;
  const int nt = swz & (NT - 1);

  int row0, valid, eidx = 0;
  if constexpr (EXPERT) {
    if (mt >= routing[R_TOTAL]) return;
    int e = 0;
    while (e < 7 && routing[R_TSTART + e + 1] <= mt) ++e;
    eidx = e;
    int lm = mt - routing[R_TSTART + e];
    row0 = routing[R_OFFSET + e] + lm * 128;
    valid = min(128, routing[R_COUNTS + e] - lm * 128);
  } else {
    row0 = mt * 128;
    valid = 128;
  }

  const bf16_t* Bexp = Bw + (EXPERT ? (size_t)eidx * NTOT * K : 0);
  const float* biasp = bias + (EXPERT ? eidx * NTOT : 0);

  const int sub = t >> 3;                     // 0..31
  const int lc = (t & 7) ^ (sub & 7);
  const bf16_t* aS[4];
  const bf16_t* bS[4];
#pragma unroll
  for (int i = 0; i < 4; ++i) {
    int lr = sub + i * 32;                    // 0..127
    int gr;
    if constexpr (MODE == 0) {
      gr = perm[row0 + min(lr, valid - 1)] >> 1;
    } else if constexpr (MODE == 1) {
      gr = row0 + min(lr, valid - 1);
    } else {
      gr = row0 + lr;
    }
    aS[i] = A + (size_t)gr * K + lc * 8;
    bS[i] = Bexp + (size_t)(nt * 128 + lr) * K + lc * 8;
  }
  bf16_t* const aD = lds + (sub << 6) + ((t & 7) << 3);
  bf16_t* const bD = aD + 8192;

  const int l15 = lane & 15, lq = lane >> 4;

  f32x4 acc[4][4];
#pragma unroll
  for (int m = 0; m < 4; ++m)
#pragma unroll
    for (int n = 0; n < 4; ++n) acc[m][n] = f32x4{0.f, 0.f, 0.f, 0.f};

  for (int kt = 0; kt < NKT; ++kt) {
    const size_t kof = (size_t)kt * 64;
#pragma unroll
    for (int i = 0; i < 4; ++i) {
      GLL(aS[i] + kof, aD + i * 2048);
      GLL(bS[i] + kof, bD + i * 2048);
    }
    __syncthreads();

#pragma unroll
    for (int kk = 0; kk < 2; ++kk) {
      bf16x8 af[4], bfr[4];
#pragma unroll
      for (int m = 0; m < 4; ++m) {
        int ra = wm * 64 + m * 16 + l15;
        int ph = (kk * 4 + lq) ^ (ra & 7);
        af[m] = *reinterpret_cast<const bf16x8*>(&lds[ra * 64 + ph * 8]);
      }
#pragma unroll
      for (int n = 0; n < 4; ++n) {
        int rb = wn * 64 + n * 16 + l15;
        int ph = (kk * 4 + lq) ^ (rb & 7);
        bfr[n] = *reinterpret_cast<const bf16x8*>(&lds[8192 + rb * 64 + ph * 8]);
      }
      __builtin_amdgcn_s_setprio(1);
#pragma unroll
      for (int m = 0; m < 4; ++m)
#pragma unroll
        for (int n = 0; n < 4; ++n)
          acc[m][n] = __builtin_amdgcn_mfma_f32_16x16x32_bf16(af[m], bfr[n], acc[m][n], 0, 0, 0);
      __builtin_amdgcn_s_setprio(0);
    }
    __syncthreads();
  }

  float bc[4];
#pragma unroll
  for (int n = 0; n < 4; ++n) bc[n] = biasp[nt * 128 + wn * 64 + n * 16 + l15];

  if constexpr (G1) {
    bf16_t* scr = lds;
#pragma unroll
    for (int h = 0; h < 2; ++h) {
      __syncthreads();
      if (wm == h) {
#pragma unroll
        for (int m = 0; m < 4; ++m)
#pragma unroll
          for (int n = 0; n < 4; ++n)
#pragma unroll
            for (int rr = 0; rr < 4; ++rr) {
              float v = acc[m][n][rr] + bc[n];
              scr[(m * 16 + lq * 4 + rr) * 128 + wn * 64 + n * 16 + l15] = (bf16_t)fast_gelu(v);
            }
      }
      __syncthreads();
#pragma unroll
      for (int i = 0; i < 4; ++i) {
        int c = t + i * 256;
        int rowp = c >> 4, cc = c & 15;
        int lr = h * 64 + rowp;
        if (lr < valid) {
          bf16x8 v8 = *reinterpret_cast<const bf16x8*>(&scr[rowp * 128 + cc * 8]);
          *reinterpret_cast<bf16x8*>(&Hout[(size_t)(row0 + lr) * OUTD + nt * 128 + cc * 8]) = v8;
        }
      }
    }
  } else {
    float* scr = reinterpret_cast<float*>(lds);
#pragma unroll
    for (int h = 0; h < 2; ++h) {
      __syncthreads();
      if (wm == h) {
#pragma unroll
        for (int m = 0; m < 4; ++m)
#pragma unroll
          for (int n = 0; n < 4; ++n)
#pragma unroll
            for (int rr = 0; rr < 4; ++rr)
              scr[(m * 16 + lq * 4 + rr) * 128 + wn * 64 + n * 16 + l15] = acc[m][n][rr] + bc[n];
      }
      __syncthreads();
#pragma unroll
      for (int i = 0; i < 8; ++i) {
        int c = t + i * 256;
        int rowp = c >> 5, cc = c & 31;
        int lr = h * 64 + rowp;
        if (lr < valid) {
          float4 v4 = *reinterpret_cast<const float4*>(&scr[rowp * 128 + cc * 4]);
          *reinterpret_cast<float4*>(&out[(size_t)(row0 + lr) * OUTD + nt * 128 + cc * 4]) = v4;
        }
      }
    }
  }
}

// ---------------------------------------------------------------- launch
extern "C" void kernel_launch(void* const* d_in, const int* in_sizes, int n_in,
                              void* d_out, int out_size, void* d_ws, size_t ws_size,
                              hipStream_t stream) {
  const float* x   = (const float*)d_in[0];
  const float* gw  = (const float*)d_in[1];
  const float* w1  = (const float*)d_in[2];
  const float* b1  = (const float*)d_in[3];
  const float* w2  = (const float*)d_in[4];
  const float* b2  = (const float*)d_in[5];
  const float* sw1 = (const float*)d_in[6];
  const float* sb1 = (const float*)d_in[7];
  const float* sw2 = (const float*)d_in[8];
  const float* sb2 = (const float*)d_in[9];
  float* out = (float*)d_out;

  char* ws = (char*)d_ws;
  bf16_t* xb    = (bf16_t*)(ws);                          // 16 MB  [dead after expert G1]
  bf16_t* w1b   = (bf16_t*)(ws + ((size_t)16 << 20));     // 64 MB  [dead after expert G1]
  bf16_t* w2b   = (bf16_t*)(ws + ((size_t)80 << 20));     // 64 MB
  bf16_t* sw1b  = (bf16_t*)(ws + ((size_t)144 << 20));    // 8 MB
  bf16_t* sw2b  = (bf16_t*)(ws + ((size_t)152 << 20));    // 8 MB
  bf16_t* Hbuf  = (bf16_t*)(ws + ((size_t)160 << 20));    // 128 MB (16384 x 4096 bf16)
  float*  slotbuf = (float*)(ws);                         // 67 MB, overlaps xb+w1b (dead by then)
  float*  topkw = (float*)(ws + ((size_t)288 << 20));     // 64 KB
  int*    slote = (int*)(ws + ((size_t)288 << 20) + 65536);
  int*    perm  = (int*)(ws + ((size_t)288 << 20) + 2 * 65536);
  int*    pos   = (int*)(ws + ((size_t)288 << 20) + 3 * 65536);
  int*    routing = (int*)(ws + ((size_t)288 << 20) + 4 * 65536);

  // fp32 -> bf16 conversions
  cvt_f32_bf16<<<(TT * DD / 8 + 255) / 256, 256, 0, stream>>>(x, xb, TT * DD / 8);
  cvt_f32_bf16<<<(8 * FF * DD / 8 + 255) / 256, 256, 0, stream>>>(w1, w1b, 8 * FF * DD / 8);
  cvt_f32_bf16<<<(8 * DD * FF / 8 + 255) / 256, 256, 0, stream>>>(w2, w2b, 8 * DD * FF / 8);
  cvt_f32_bf16<<<(FF * DD / 8 + 255) / 256, 256, 0, stream>>>(sw1, sw1b, FF * DD / 8);
  cvt_f32_bf16<<<(DD * FF / 8 + 255) / 256, 256, 0, stream>>>(sw2, sw2b, DD * FF / 8);

  // routing (no global atomics anywhere)
  gate_kernel<<<TT / 4, 256, 0, stream>>>(x, gw, topkw, slote);
  hist_kernel<<<8, 256, 0, stream>>>(slote, routing);
  scan_kernel<<<1, 1, 0, stream>>>(routing);
  scatter_kernel<<<8, 256, 0, stream>>>(slote, routing, perm, pos);

  // shared expert first (plain store covers all of out), then experts into slotbuf
  gemm_kernel<2><<<64 * 32, 256, 0, stream>>>(xb, sw1b, sb1, Hbuf, out, routing, perm);
  gemm_kernel<3><<<64 * 8, 256, 0, stream>>>(Hbuf, sw2b, sb2, nullptr, out, routing, perm);
  gemm_kernel<0><<<136 * 32, 256, 0, stream>>>(xb, w1b, b1, Hbuf, out, routing, perm);
  gemm_kernel<1><<<136 * 8, 256, 0, stream>>>(Hbuf, w2b, b2, nullptr, slotbuf, routing, perm);

  // out += gate-weighted expert contributions
  combine_kernel<<<TT, 256, 0, stream>>>(slotbuf, pos, topkw, out);
}

// Round 11
// 697.921 us; speedup vs baseline: 2.1342x; 1.0170x over previous
//
#include <hip/hip_runtime.h>
#include <hip/hip_bf16.h>

typedef __bf16 bf16_t;
typedef __bf16 bf16x8 __attribute__((ext_vector_type(8)));
typedef float  f32x4  __attribute__((ext_vector_type(4)));

static constexpr int TT = 8192;     // tokens (2*4096)
static constexpr int DD = 1024;
static constexpr int FF = 4096;
static constexpr int NSLOT = 2 * TT;  // 16384 (token, k) slots

// routing int-array layout
#define R_COUNTS 0
#define R_OFFSET 8
#define R_TSTART 17
#define R_TOTAL  34
#define R_INTS   40

#define GLL(g, l) __builtin_amdgcn_global_load_lds( \
    (__attribute__((address_space(1))) void*)(g), \
    (__attribute__((address_space(3))) void*)(l), 16, 0, 0)

__device__ __forceinline__ float fast_gelu(float v) {
  float t = -1.5957691216f * v - 0.0713548162f * (v * v * v);
  return v / (1.f + __expf(t));
}

// ---------------------------------------------------------------- convert
__global__ __launch_bounds__(256) void cvt_f32_bf16(const float* __restrict__ src,
                                                    bf16_t* __restrict__ dst, int n8) {
  int i = blockIdx.x * 256 + threadIdx.x;
  if (i >= n8) return;
  const float4* s = reinterpret_cast<const float4*>(src) + (size_t)i * 2;
  float4 a = s[0], b = s[1];
  bf16x8 v;
  v[0] = (bf16_t)a.x; v[1] = (bf16_t)a.y; v[2] = (bf16_t)a.z; v[3] = (bf16_t)a.w;
  v[4] = (bf16_t)b.x; v[5] = (bf16_t)b.y; v[6] = (bf16_t)b.z; v[7] = (bf16_t)b.w;
  *reinterpret_cast<bf16x8*>(dst + (size_t)i * 8) = v;
}

// ---------------------------------------------------------------- gate (no atomics; also emits xb)
__global__ __launch_bounds__(256) void gate_kernel(const float* __restrict__ x,
                                                   const float* __restrict__ gw,
                                                   float* __restrict__ topkw,
                                                   int* __restrict__ slote,
                                                   bf16_t* __restrict__ xb) {
  int wid = threadIdx.x >> 6, lane = threadIdx.x & 63;
  int t = blockIdx.x * 4 + wid;
  const float4* xv = reinterpret_cast<const float4*>(x + (size_t)t * DD) + lane * 4;
  const float4* gv = reinterpret_cast<const float4*>(gw);
  float acc[8];
  float4 xs[4];
#pragma unroll
  for (int e = 0; e < 8; ++e) acc[e] = 0.f;
#pragma unroll
  for (int i = 0; i < 4; ++i) {
    float4 xi = xv[i];
    xs[i] = xi;
#pragma unroll
    for (int e = 0; e < 8; ++e) {
      float4 g = gv[e * 256 + lane * 4 + i];
      acc[e] += xi.x * g.x + xi.y * g.y + xi.z * g.z + xi.w * g.w;
    }
  }
  // write bf16 copy of this token row (replaces the x cvt kernel)
  {
    bf16x8 lo, hi;
    lo[0]=(bf16_t)xs[0].x; lo[1]=(bf16_t)xs[0].y; lo[2]=(bf16_t)xs[0].z; lo[3]=(bf16_t)xs[0].w;
    lo[4]=(bf16_t)xs[1].x; lo[5]=(bf16_t)xs[1].y; lo[6]=(bf16_t)xs[1].z; lo[7]=(bf16_t)xs[1].w;
    hi[0]=(bf16_t)xs[2].x; hi[1]=(bf16_t)xs[2].y; hi[2]=(bf16_t)xs[2].z; hi[3]=(bf16_t)xs[2].w;
    hi[4]=(bf16_t)xs[3].x; hi[5]=(bf16_t)xs[3].y; hi[6]=(bf16_t)xs[3].z; hi[7]=(bf16_t)xs[3].w;
    bf16_t* d = xb + (size_t)t * DD + lane * 16;
    *reinterpret_cast<bf16x8*>(d) = lo;
    *reinterpret_cast<bf16x8*>(d + 8) = hi;
  }
#pragma unroll
  for (int e = 0; e < 8; ++e)
    for (int off = 32; off; off >>= 1) acc[e] += __shfl_xor(acc[e], off, 64);
  if (lane == 0) {
    float m = acc[0];
#pragma unroll
    for (int e = 1; e < 8; ++e) m = fmaxf(m, acc[e]);
    float p[8], s = 0.f;
#pragma unroll
    for (int e = 0; e < 8; ++e) { p[e] = expf(acc[e] - m); s += p[e]; }
    float inv = 1.f / s;
#pragma unroll
    for (int e = 0; e < 8; ++e) p[e] *= inv;
    int e1 = 0; float b1v = p[0];
#pragma unroll
    for (int e = 1; e < 8; ++e) if (p[e] > b1v) { b1v = p[e]; e1 = e; }
    int e2 = -1; float b2v = -1.f;
#pragma unroll
    for (int e = 0; e < 8; ++e) if (e != e1 && p[e] > b2v) { b2v = p[e]; e2 = e; }
    topkw[2 * t] = b1v;  topkw[2 * t + 1] = b2v;
    slote[2 * t] = e1;   slote[2 * t + 1] = e2;
  }
}

// ---------------------------------------------------------------- histogram (8 blocks, no atomics)
__global__ __launch_bounds__(256) void hist_kernel(const int* __restrict__ slote,
                                                   int* __restrict__ routing) {
  __shared__ int red[256];
  const int e = blockIdx.x;
  const int t = threadIdx.x;
  int cnt = 0;
  for (int base = 0; base < NSLOT; base += 256)
    cnt += (slote[base + t] == e) ? 1 : 0;
  red[t] = cnt;
  __syncthreads();
  for (int s = 128; s; s >>= 1) {
    if (t < s) red[t] += red[t + s];
    __syncthreads();
  }
  if (t == 0) routing[R_COUNTS + e] = red[0];
}

// ---------------------------------------------------------------- scan (1 thread)
__global__ void scan_kernel(int* __restrict__ routing) {
  int off = 0, tt = 0;
  for (int e = 0; e < 8; ++e) {
    routing[R_OFFSET + e] = off;
    routing[R_TSTART + e] = tt;
    int c = routing[R_COUNTS + e];
    off += c;
    tt += (c + 127) >> 7;   // 128-row M-tiles
  }
  routing[R_OFFSET + 8] = off;
  routing[R_TSTART + 8] = tt;
  routing[R_TOTAL] = tt;
}

// ---------------------------------------------------------------- scatter (8 blocks, stable, no atomics)
__global__ __launch_bounds__(256) void scatter_kernel(const int* __restrict__ slote,
                                                      const int* __restrict__ routing,
                                                      int* __restrict__ perm,
                                                      int* __restrict__ pos) {
  __shared__ int wtot[4];
  const int e = blockIdx.x;
  const int t = threadIdx.x;
  const int lane = t & 63, wid = t >> 6;
  int running = routing[R_OFFSET + e];
  for (int base = 0; base < NSLOT; base += 256) {
    int s = base + t;
    bool m = (slote[s] == e);
    unsigned long long mask = __ballot(m);
    int wrank = __popcll(mask & ((1ull << lane) - 1ull));
    if (lane == 0) wtot[wid] = __popcll(mask);
    __syncthreads();
    int wpre = 0;
#pragma unroll
    for (int w = 0; w < 4; ++w) if (w < wid) wpre += wtot[w];
    int tot = wtot[0] + wtot[1] + wtot[2] + wtot[3];
    if (m) {
      int pp = running + wpre + wrank;
      perm[pp] = s;
      pos[s] = pp;
    }
    running += tot;
    __syncthreads();
  }
}

// ---------------------------------------------------------------- combine: out += slot0 + slot1
__global__ __launch_bounds__(256) void combine_kernel(const bf16_t* __restrict__ slotb,
                                                      const int* __restrict__ pos,
                                                      float* __restrict__ out) {
  int idx = blockIdx.x * 256 + threadIdx.x;   // one 8-col chunk per thread
  int t = idx >> 7;                            // DD/8 = 128 chunks per token
  int c = (idx & 127) << 3;
  int p0 = pos[2 * t], p1 = pos[2 * t + 1];
  bf16x8 s0 = *reinterpret_cast<const bf16x8*>(&slotb[(size_t)p0 * DD + c]);
  bf16x8 s1 = *reinterpret_cast<const bf16x8*>(&slotb[(size_t)p1 * DD + c]);
  float* o = &out[(size_t)t * DD + c];
  float4 o0 = *reinterpret_cast<const float4*>(o);
  float4 o1 = *reinterpret_cast<const float4*>(o + 4);
  o0.x += (float)s0[0] + (float)s1[0];
  o0.y += (float)s0[1] + (float)s1[1];
  o0.z += (float)s0[2] + (float)s1[2];
  o0.w += (float)s0[3] + (float)s1[3];
  o1.x += (float)s0[4] + (float)s1[4];
  o1.y += (float)s0[5] + (float)s1[5];
  o1.z += (float)s0[6] + (float)s1[6];
  o1.w += (float)s0[7] + (float)s1[7];
  *reinterpret_cast<float4*>(o) = o0;
  *reinterpret_cast<float4*>(o + 4) = o1;
}

// ---------------------------------------------------------------- GEMM (m97 replica loop; unchanged)
// 128x128 tile, BK=64, 256 threads / 4 waves (2x2), SINGLE 32 KB LDS buffer,
// loop = {STAGE(kt); sync; ds_read+MFMA; sync}. Swizzle phys = log ^ (row&7), both sides.
// MODE 0: expert G1 (A via perm, K=1024) -> fast_gelu -> H (bf16)
// MODE 1: expert G2 (A = H rows, K=4096) -> w_slot*(acc+b2) -> slotb (bf16)
// MODE 2: shared G1 (A = x direct, K=1024) -> fast_gelu -> H (bf16)
// MODE 3: shared G2 (A = H rows, K=4096) -> plain store out (+sb2, fp32)
template <int MODE>
__global__ __launch_bounds__(256, 4) void gemm_kernel(
    const bf16_t* __restrict__ A, const bf16_t* __restrict__ Bw,
    const float* __restrict__ bias, bf16_t* __restrict__ Hout,
    float* __restrict__ out, const int* __restrict__ routing,
    const int* __restrict__ perm, const float* __restrict__ topkw) {
  constexpr bool EXPERT = (MODE < 2);
  constexpr int K = (MODE == 0 || MODE == 2) ? 1024 : 4096;
  constexpr int NTOT = (MODE == 0 || MODE == 2) ? 4096 : 1024;
  constexpr int NT = NTOT / 128;   // 32 or 8 (pow2)
  constexpr int NKT = K / 64;      // 16 or 64
  constexpr int OUTD = (MODE == 0 || MODE == 2) ? FF : DD;

  __shared__ __align__(16) bf16_t lds[16384];
  __shared__ float wrow[128];

  const int t = threadIdx.x;
  const int lane = t & 63;
  const int wid = t >> 6;          // 0..3
  const int wm = wid >> 1;         // 0..1
  const int wn = wid & 1;          // 0..1

  const int nwg = gridDim.x;
  const int q = nwg >> 3, r = nwg & 7;
  const int xcd = blockIdx.x & 7, bi = blockIdx.x >> 3;
  const int swz = (xcd < r ? xcd * (q + 1) : r * (q + 1) + (xcd - r) * q) + bi;
  const int mt = swz / NT;
  const int nt = swz & (NT - 1);

  int row0, valid, eidx = 0;
  if constexpr (EXPERT) {
    if (mt >= routing[R_TOTAL]) return;
    int e = 0;
    while (e < 7 && routing[R_TSTART + e + 1] <= mt) ++e;
    eidx = e;
    int lm = mt - routing[R_TSTART + e];
    row0 = routing[R_OFFSET + e] + lm * 128;
    valid = min(128, routing[R_COUNTS + e] - lm * 128);
  } else {
    row0 = mt * 128;
    valid = 128;
  }

  const bf16_t* Bexp = Bw + (EXPERT ? (size_t)eidx * NTOT * K : 0);
  const float* biasp = bias + (EXPERT ? eidx * NTOT : 0);

  const int sub = t >> 3;                     // 0..31
  const int lc = (t & 7) ^ (sub & 7);
  const bf16_t* aS[4];
  const bf16_t* bS[4];
#pragma unroll
  for (int i = 0; i < 4; ++i) {
    int lr = sub + i * 32;                    // 0..127
    int gr;
    if constexpr (MODE == 0) {
      gr = perm[row0 + min(lr, valid - 1)] >> 1;
    } else if constexpr (MODE == 1) {
      gr = row0 + min(lr, valid - 1);
    } else {
      gr = row0 + lr;
    }
    aS[i] = A + (size_t)gr * K + lc * 8;
    bS[i] = Bexp + (size_t)(nt * 128 + lr) * K + lc * 8;
  }
  bf16_t* const aD = lds + (sub << 6) + ((t & 7) << 3);
  bf16_t* const bD = aD + 8192;

  const int l15 = lane & 15, lq = lane >> 4;

  f32x4 acc[4][4];
#pragma unroll
  for (int m = 0; m < 4; ++m)
#pragma unroll
    for (int n = 0; n < 4; ++n) acc[m][n] = f32x4{0.f, 0.f, 0.f, 0.f};

  for (int kt = 0; kt < NKT; ++kt) {
    const size_t kof = (size_t)kt * 64;
#pragma unroll
    for (int i = 0; i < 4; ++i) {
      GLL(aS[i] + kof, aD + i * 2048);
      GLL(bS[i] + kof, bD + i * 2048);
    }
    __syncthreads();

#pragma unroll
    for (int kk = 0; kk < 2; ++kk) {
      bf16x8 af[4], bfr[4];
#pragma unroll
      for (int m = 0; m < 4; ++m) {
        int ra = wm * 64 + m * 16 + l15;
        int ph = (kk * 4 + lq) ^ (ra & 7);
        af[m] = *reinterpret_cast<const bf16x8*>(&lds[ra * 64 + ph * 8]);
      }
#pragma unroll
      for (int n = 0; n < 4; ++n) {
        int rb = wn * 64 + n * 16 + l15;
        int ph = (kk * 4 + lq) ^ (rb & 7);
        bfr[n] = *reinterpret_cast<const bf16x8*>(&lds[8192 + rb * 64 + ph * 8]);
      }
      __builtin_amdgcn_s_setprio(1);
#pragma unroll
      for (int m = 0; m < 4; ++m)
#pragma unroll
        for (int n = 0; n < 4; ++n)
          acc[m][n] = __builtin_amdgcn_mfma_f32_16x16x32_bf16(af[m], bfr[n], acc[m][n], 0, 0, 0);
      __builtin_amdgcn_s_setprio(0);
    }
    __syncthreads();
  }

  // slot gate weights for MODE 1 (folded combine weight)
  if constexpr (MODE == 1) {
    if (t < 128) wrow[t] = topkw[perm[row0 + min(t, valid - 1)]];
  }

  float bc[4];
#pragma unroll
  for (int n = 0; n < 4; ++n) bc[n] = biasp[nt * 128 + wn * 64 + n * 16 + l15];

  // ---- epilogue via LDS transpose: coalesced vector stores.
  // C/D frag: col = lane&15, row = (lane>>4)*4 + rr  [m89-verified]
  if constexpr (MODE != 3) {
    bf16_t* scr = lds;   // 64 x 128 bf16 = 16 KB per half
#pragma unroll
    for (int h = 0; h < 2; ++h) {
      __syncthreads();
      if (wm == h) {
#pragma unroll
        for (int m = 0; m < 4; ++m)
#pragma unroll
          for (int n = 0; n < 4; ++n)
#pragma unroll
            for (int rr = 0; rr < 4; ++rr) {
              float v = acc[m][n][rr] + bc[n];
              float o;
              if constexpr (MODE == 1) o = wrow[h * 64 + m * 16 + lq * 4 + rr] * v;
              else                     o = fast_gelu(v);
              scr[(m * 16 + lq * 4 + rr) * 128 + wn * 64 + n * 16 + l15] = (bf16_t)o;
            }
      }
      __syncthreads();
#pragma unroll
      for (int i = 0; i < 4; ++i) {
        int c = t + i * 256;
        int rowp = c >> 4, cc = c & 15;
        int lr = h * 64 + rowp;
        if (lr < valid) {
          bf16x8 v8 = *reinterpret_cast<const bf16x8*>(&scr[rowp * 128 + cc * 8]);
          *reinterpret_cast<bf16x8*>(&Hout[(size_t)(row0 + lr) * OUTD + nt * 128 + cc * 8]) = v8;
        }
      }
    }
  } else {
    float* scr = reinterpret_cast<float*>(lds);   // 64 x 128 f32 = 32 KB per half
#pragma unroll
    for (int h = 0; h < 2; ++h) {
      __syncthreads();
      if (wm == h) {
#pragma unroll
        for (int m = 0; m < 4; ++m)
#pragma unroll
          for (int n = 0; n < 4; ++n)
#pragma unroll
            for (int rr = 0; rr < 4; ++rr)
              scr[(m * 16 + lq * 4 + rr) * 128 + wn * 64 + n * 16 + l15] = acc[m][n][rr] + bc[n];
      }
      __syncthreads();
#pragma unroll
      for (int i = 0; i < 8; ++i) {
        int c = t + i * 256;
        int rowp = c >> 5, cc = c & 31;
        int lr = h * 64 + rowp;
        float4 v4 = *reinterpret_cast<const float4*>(&scr[rowp * 128 + cc * 4]);
        *reinterpret_cast<float4*>(&out[(size_t)(row0 + lr) * OUTD + nt * 128 + cc * 4]) = v4;
      }
    }
  }
}

// ---------------------------------------------------------------- launch
extern "C" void kernel_launch(void* const* d_in, const int* in_sizes, int n_in,
                              void* d_out, int out_size, void* d_ws, size_t ws_size,
                              hipStream_t stream) {
  const float* x   = (const float*)d_in[0];
  const float* gw  = (const float*)d_in[1];
  const float* w1  = (const float*)d_in[2];
  const float* b1  = (const float*)d_in[3];
  const float* w2  = (const float*)d_in[4];
  const float* b2  = (const float*)d_in[5];
  const float* sw1 = (const float*)d_in[6];
  const float* sb1 = (const float*)d_in[7];
  const float* sw2 = (const float*)d_in[8];
  const float* sb2 = (const float*)d_in[9];
  float* out = (float*)d_out;

  char* ws = (char*)d_ws;
  bf16_t* xb    = (bf16_t*)(ws);                          // 16 MB  [dead after expert G1]
  bf16_t* w1b   = (bf16_t*)(ws + ((size_t)16 << 20));     // 64 MB  [dead after expert G1]
  bf16_t* w2b   = (bf16_t*)(ws + ((size_t)80 << 20));     // 64 MB
  bf16_t* sw1b  = (bf16_t*)(ws + ((size_t)144 << 20));    // 8 MB
  bf16_t* sw2b  = (bf16_t*)(ws + ((size_t)152 << 20));    // 8 MB
  bf16_t* Hbuf  = (bf16_t*)(ws + ((size_t)160 << 20));    // 128 MB (16384 x 4096 bf16)
  bf16_t* slotb = (bf16_t*)(ws);                          // 32 MB bf16, overlaps xb+w1b (dead by then)
  float*  topkw = (float*)(ws + ((size_t)288 << 20));     // 64 KB
  int*    slote = (int*)(ws + ((size_t)288 << 20) + 65536);
  int*    perm  = (int*)(ws + ((size_t)288 << 20) + 2 * 65536);
  int*    pos   = (int*)(ws + ((size_t)288 << 20) + 3 * 65536);
  int*    routing = (int*)(ws + ((size_t)288 << 20) + 4 * 65536);

  // fp32 -> bf16 conversions (x is converted inside gate_kernel)
  cvt_f32_bf16<<<(8 * FF * DD / 8 + 255) / 256, 256, 0, stream>>>(w1, w1b, 8 * FF * DD / 8);
  cvt_f32_bf16<<<(8 * DD * FF / 8 + 255) / 256, 256, 0, stream>>>(w2, w2b, 8 * DD * FF / 8);
  cvt_f32_bf16<<<(FF * DD / 8 + 255) / 256, 256, 0, stream>>>(sw1, sw1b, FF * DD / 8);
  cvt_f32_bf16<<<(DD * FF / 8 + 255) / 256, 256, 0, stream>>>(sw2, sw2b, DD * FF / 8);

  // routing (no global atomics anywhere)
  gate_kernel<<<TT / 4, 256, 0, stream>>>(x, gw, topkw, slote, xb);
  hist_kernel<<<8, 256, 0, stream>>>(slote, routing);
  scan_kernel<<<1, 1, 0, stream>>>(routing);
  scatter_kernel<<<8, 256, 0, stream>>>(slote, routing, perm, pos);

  // shared expert first (plain store covers all of out), then experts into slotb
  gemm_kernel<2><<<64 * 32, 256, 0, stream>>>(xb, sw1b, sb1, Hbuf, out, routing, perm, nullptr);
  gemm_kernel<3><<<64 * 8, 256, 0, stream>>>(Hbuf, sw2b, sb2, nullptr, out, routing, perm, nullptr);
  gemm_kernel<0><<<136 * 32, 256, 0, stream>>>(xb, w1b, b1, Hbuf, out, routing, perm, nullptr);
  gemm_kernel<1><<<136 * 8, 256, 0, stream>>>(Hbuf, w2b, b2, slotb, nullptr, routing, perm, topkw);

  // out += expert contributions (weights already folded in)
  combine_kernel<<<TT * DD / 8 / 256, 256, 0, stream>>>(slotb, pos, out);
}

// Round 12
// 695.589 us; speedup vs baseline: 2.1414x; 1.0034x over previous
//
#include <hip/hip_runtime.h>
#include <hip/hip_bf16.h>

typedef __bf16 bf16_t;
typedef __bf16 bf16x4 __attribute__((ext_vector_type(4)));
typedef __bf16 bf16x8 __attribute__((ext_vector_type(8)));
typedef float  f32x4  __attribute__((ext_vector_type(4)));

static constexpr int TT = 8192;     // tokens (2*4096)
static constexpr int DD = 1024;
static constexpr int FF = 4096;
static constexpr int NSLOT = 2 * TT;  // 16384 (token, k) slots

// routing int-array layout
#define R_COUNTS 0
#define R_OFFSET 8
#define R_TSTART 17
#define R_TOTAL  34
#define R_INTS   40

#define GLL(g, l) __builtin_amdgcn_global_load_lds( \
    (__attribute__((address_space(1))) void*)(g), \
    (__attribute__((address_space(3))) void*)(l), 16, 0, 0)

__device__ __forceinline__ float fast_gelu(float v) {
  float t = -1.5957691216f * v - 0.0713548162f * (v * v * v);
  return v / (1.f + __expf(t));
}

// ---------------------------------------------------------------- convert
__global__ __launch_bounds__(256) void cvt_f32_bf16(const float* __restrict__ src,
                                                    bf16_t* __restrict__ dst, int n8) {
  int i = blockIdx.x * 256 + threadIdx.x;
  if (i >= n8) return;
  const float4* s = reinterpret_cast<const float4*>(src) + (size_t)i * 2;
  float4 a = s[0], b = s[1];
  bf16x8 v;
  v[0] = (bf16_t)a.x; v[1] = (bf16_t)a.y; v[2] = (bf16_t)a.z; v[3] = (bf16_t)a.w;
  v[4] = (bf16_t)b.x; v[5] = (bf16_t)b.y; v[6] = (bf16_t)b.z; v[7] = (bf16_t)b.w;
  *reinterpret_cast<bf16x8*>(dst + (size_t)i * 8) = v;
}

// ---------------------------------------------------------------- gate (no atomics; also emits xb)
__global__ __launch_bounds__(256) void gate_kernel(const float* __restrict__ x,
                                                   const float* __restrict__ gw,
                                                   float* __restrict__ topkw,
                                                   int* __restrict__ slote,
                                                   bf16_t* __restrict__ xb) {
  int wid = threadIdx.x >> 6, lane = threadIdx.x & 63;
  int t = blockIdx.x * 4 + wid;
  const float4* xv = reinterpret_cast<const float4*>(x + (size_t)t * DD) + lane * 4;
  const float4* gv = reinterpret_cast<const float4*>(gw);
  float acc[8];
  float4 xs[4];
#pragma unroll
  for (int e = 0; e < 8; ++e) acc[e] = 0.f;
#pragma unroll
  for (int i = 0; i < 4; ++i) {
    float4 xi = xv[i];
    xs[i] = xi;
#pragma unroll
    for (int e = 0; e < 8; ++e) {
      float4 g = gv[e * 256 + lane * 4 + i];
      acc[e] += xi.x * g.x + xi.y * g.y + xi.z * g.z + xi.w * g.w;
    }
  }
  {
    bf16x8 lo, hi;
    lo[0]=(bf16_t)xs[0].x; lo[1]=(bf16_t)xs[0].y; lo[2]=(bf16_t)xs[0].z; lo[3]=(bf16_t)xs[0].w;
    lo[4]=(bf16_t)xs[1].x; lo[5]=(bf16_t)xs[1].y; lo[6]=(bf16_t)xs[1].z; lo[7]=(bf16_t)xs[1].w;
    hi[0]=(bf16_t)xs[2].x; hi[1]=(bf16_t)xs[2].y; hi[2]=(bf16_t)xs[2].z; hi[3]=(bf16_t)xs[2].w;
    hi[4]=(bf16_t)xs[3].x; hi[5]=(bf16_t)xs[3].y; hi[6]=(bf16_t)xs[3].z; hi[7]=(bf16_t)xs[3].w;
    bf16_t* d = xb + (size_t)t * DD + lane * 16;
    *reinterpret_cast<bf16x8*>(d) = lo;
    *reinterpret_cast<bf16x8*>(d + 8) = hi;
  }
#pragma unroll
  for (int e = 0; e < 8; ++e)
    for (int off = 32; off; off >>= 1) acc[e] += __shfl_xor(acc[e], off, 64);
  if (lane == 0) {
    float m = acc[0];
#pragma unroll
    for (int e = 1; e < 8; ++e) m = fmaxf(m, acc[e]);
    float p[8], s = 0.f;
#pragma unroll
    for (int e = 0; e < 8; ++e) { p[e] = expf(acc[e] - m); s += p[e]; }
    float inv = 1.f / s;
#pragma unroll
    for (int e = 0; e < 8; ++e) p[e] *= inv;
    int e1 = 0; float b1v = p[0];
#pragma unroll
    for (int e = 1; e < 8; ++e) if (p[e] > b1v) { b1v = p[e]; e1 = e; }
    int e2 = -1; float b2v = -1.f;
#pragma unroll
    for (int e = 0; e < 8; ++e) if (e != e1 && p[e] > b2v) { b2v = p[e]; e2 = e; }
    topkw[2 * t] = b1v;  topkw[2 * t + 1] = b2v;
    slote[2 * t] = e1;   slote[2 * t + 1] = e2;
  }
}

// ---------------------------------------------------------------- fused routing (8 blocks, no atomics)
// Each block: slote -> LDS, full 8-expert histogram (local), own offset, stable scatter.
__global__ __launch_bounds__(256) void route_kernel(const int* __restrict__ slote,
                                                    int* __restrict__ routing,
                                                    int* __restrict__ perm,
                                                    int* __restrict__ pos) {
  __shared__ int sl[NSLOT > 16384 ? 1 : 16384];   // 64 KB
  __shared__ int red[256];
  __shared__ int wtot[4];
  const int e = blockIdx.x;
  const int t = threadIdx.x;
  const int lane = t & 63, wid = t >> 6;

  for (int i = t; i < NSLOT; i += 256) sl[i] = slote[i];
  __syncthreads();

  int cnt[8];
#pragma unroll
  for (int ee = 0; ee < 8; ++ee) cnt[ee] = 0;
  for (int i = t; i < NSLOT; i += 256) ++cnt[sl[i]];

  int tot[8];
#pragma unroll
  for (int ee = 0; ee < 8; ++ee) {
    red[t] = cnt[ee];
    __syncthreads();
    for (int s = 128; s; s >>= 1) {
      if (t < s) red[t] += red[t + s];
      __syncthreads();
    }
    tot[ee] = red[0];
    __syncthreads();
  }

  int offarr[9], tstart[9];
  {
    int off = 0, tts = 0;
#pragma unroll
    for (int ee = 0; ee < 8; ++ee) {
      offarr[ee] = off; tstart[ee] = tts;
      off += tot[ee]; tts += (tot[ee] + 127) >> 7;
    }
    offarr[8] = off; tstart[8] = tts;
  }
  if (e == 0 && t == 0) {
#pragma unroll
    for (int ee = 0; ee < 8; ++ee) routing[R_COUNTS + ee] = tot[ee];
#pragma unroll
    for (int ee = 0; ee < 9; ++ee) {
      routing[R_OFFSET + ee] = offarr[ee];
      routing[R_TSTART + ee] = tstart[ee];
    }
    routing[R_TOTAL] = tstart[8];
  }

  int running = offarr[e];
  for (int base = 0; base < NSLOT; base += 256) {
    int s = base + t;
    bool m = (sl[s] == e);
    unsigned long long mask = __ballot(m);
    int wrank = __popcll(mask & ((1ull << lane) - 1ull));
    if (lane == 0) wtot[wid] = __popcll(mask);
    __syncthreads();
    int wpre = 0;
#pragma unroll
    for (int w = 0; w < 4; ++w) if (w < wid) wpre += wtot[w];
    int totb = wtot[0] + wtot[1] + wtot[2] + wtot[3];
    if (m) {
      int pp = running + wpre + wrank;
      perm[pp] = s;
      pos[s] = pp;
    }
    running += totb;
    __syncthreads();
  }
}

// ---------------------------------------------------------------- GEMM (m97 replica loop; frozen)
// 128x128 tile, BK=64, 256 threads / 4 waves (2x2), SINGLE 32 KB LDS buffer,
// loop = {STAGE(kt); sync; ds_read+MFMA; sync}. Swizzle phys = log ^ (row&7), both sides.
// MODE 0: expert G1 (A via perm, K=1024) -> fast_gelu -> H (bf16)
// MODE 1: expert G2 (A = H rows, K=4096) -> w_slot*(acc+b2) -> slotb (bf16)
// MODE 2: shared G1 (A = x direct, K=1024) -> fast_gelu -> H (bf16)
// MODE 3: shared G2 (A = H rows, K=4096) -> out = acc+sb2+slotb[pos0]+slotb[pos1] (fused combine)
template <int MODE>
__global__ __launch_bounds__(256, 4) void gemm_kernel(
    const bf16_t* __restrict__ A, const bf16_t* __restrict__ Bw,
    const float* __restrict__ bias, bf16_t* __restrict__ Hout,
    float* __restrict__ out, const int* __restrict__ routing,
    const int* __restrict__ perm, const float* __restrict__ topkw,
    const int* __restrict__ pos, const bf16_t* __restrict__ slotb) {
  constexpr bool EXPERT = (MODE < 2);
  constexpr int K = (MODE == 0 || MODE == 2) ? 1024 : 4096;
  constexpr int NTOT = (MODE == 0 || MODE == 2) ? 4096 : 1024;
  constexpr int NT = NTOT / 128;   // 32 or 8 (pow2)
  constexpr int NKT = K / 64;      // 16 or 64
  constexpr int OUTD = (MODE == 0 || MODE == 2) ? FF : DD;

  __shared__ __align__(16) bf16_t lds[16384];
  __shared__ float wrow[128];
  __shared__ int spos[256];

  const int t = threadIdx.x;
  const int lane = t & 63;
  const int wid = t >> 6;          // 0..3
  const int wm = wid >> 1;         // 0..1
  const int wn = wid & 1;          // 0..1

  const int nwg = gridDim.x;
  const int q = nwg >> 3, r = nwg & 7;
  const int xcd = blockIdx.x & 7, bi = blockIdx.x >> 3;
  const int swz = (xcd < r ? xcd * (q + 1) : r * (q + 1) + (xcd - r) * q) + bi;
  const int mt = swz / NT;
  const int nt = swz & (NT - 1);

  int row0, valid, eidx = 0;
  if constexpr (EXPERT) {
    if (mt >= routing[R_TOTAL]) return;
    int e = 0;
    while (e < 7 && routing[R_TSTART + e + 1] <= mt) ++e;
    eidx = e;
    int lm = mt - routing[R_TSTART + e];
    row0 = routing[R_OFFSET + e] + lm * 128;
    valid = min(128, routing[R_COUNTS + e] - lm * 128);
  } else {
    row0 = mt * 128;
    valid = 128;
  }

  const bf16_t* Bexp = Bw + (EXPERT ? (size_t)eidx * NTOT * K : 0);
  const float* biasp = bias + (EXPERT ? eidx * NTOT : 0);

  const int sub = t >> 3;                     // 0..31
  const int lc = (t & 7) ^ (sub & 7);
  const bf16_t* aS[4];
  const bf16_t* bS[4];
#pragma unroll
  for (int i = 0; i < 4; ++i) {
    int lr = sub + i * 32;                    // 0..127
    int gr;
    if constexpr (MODE == 0) {
      gr = perm[row0 + min(lr, valid - 1)] >> 1;
    } else if constexpr (MODE == 1) {
      gr = row0 + min(lr, valid - 1);
    } else {
      gr = row0 + lr;
    }
    aS[i] = A + (size_t)gr * K + lc * 8;
    bS[i] = Bexp + (size_t)(nt * 128 + lr) * K + lc * 8;
  }
  bf16_t* const aD = lds + (sub << 6) + ((t & 7) << 3);
  bf16_t* const bD = aD + 8192;

  const int l15 = lane & 15, lq = lane >> 4;

  f32x4 acc[4][4];
#pragma unroll
  for (int m = 0; m < 4; ++m)
#pragma unroll
    for (int n = 0; n < 4; ++n) acc[m][n] = f32x4{0.f, 0.f, 0.f, 0.f};

  for (int kt = 0; kt < NKT; ++kt) {
    const size_t kof = (size_t)kt * 64;
#pragma unroll
    for (int i = 0; i < 4; ++i) {
      GLL(aS[i] + kof, aD + i * 2048);
      GLL(bS[i] + kof, bD + i * 2048);
    }
    __syncthreads();

#pragma unroll
    for (int kk = 0; kk < 2; ++kk) {
      bf16x8 af[4], bfr[4];
#pragma unroll
      for (int m = 0; m < 4; ++m) {
        int ra = wm * 64 + m * 16 + l15;
        int ph = (kk * 4 + lq) ^ (ra & 7);
        af[m] = *reinterpret_cast<const bf16x8*>(&lds[ra * 64 + ph * 8]);
      }
#pragma unroll
      for (int n = 0; n < 4; ++n) {
        int rb = wn * 64 + n * 16 + l15;
        int ph = (kk * 4 + lq) ^ (rb & 7);
        bfr[n] = *reinterpret_cast<const bf16x8*>(&lds[8192 + rb * 64 + ph * 8]);
      }
      __builtin_amdgcn_s_setprio(1);
#pragma unroll
      for (int m = 0; m < 4; ++m)
#pragma unroll
        for (int n = 0; n < 4; ++n)
          acc[m][n] = __builtin_amdgcn_mfma_f32_16x16x32_bf16(af[m], bfr[n], acc[m][n], 0, 0, 0);
      __builtin_amdgcn_s_setprio(0);
    }
    __syncthreads();
  }

  if constexpr (MODE == 1) {
    if (t < 128) wrow[t] = topkw[perm[row0 + min(t, valid - 1)]];
  }
  if constexpr (MODE == 3) {
    spos[t] = pos[2 * row0 + t];
  }

  float bc[4];
#pragma unroll
  for (int n = 0; n < 4; ++n) bc[n] = biasp[nt * 128 + wn * 64 + n * 16 + l15];

  // ---- epilogue via LDS transpose: coalesced vector stores.
  if constexpr (MODE != 3) {
    bf16_t* scr = lds;   // 64 x 128 bf16 = 16 KB per half
#pragma unroll
    for (int h = 0; h < 2; ++h) {
      __syncthreads();
      if (wm == h) {
#pragma unroll
        for (int m = 0; m < 4; ++m)
#pragma unroll
          for (int n = 0; n < 4; ++n)
#pragma unroll
            for (int rr = 0; rr < 4; ++rr) {
              float v = acc[m][n][rr] + bc[n];
              float o;
              if constexpr (MODE == 1) o = wrow[h * 64 + m * 16 + lq * 4 + rr] * v;
              else                     o = fast_gelu(v);
              scr[(m * 16 + lq * 4 + rr) * 128 + wn * 64 + n * 16 + l15] = (bf16_t)o;
            }
      }
      __syncthreads();
#pragma unroll
      for (int i = 0; i < 4; ++i) {
        int c = t + i * 256;
        int rowp = c >> 4, cc = c & 15;
        int lr = h * 64 + rowp;
        if (lr < valid) {
          bf16x8 v8 = *reinterpret_cast<const bf16x8*>(&scr[rowp * 128 + cc * 8]);
          *reinterpret_cast<bf16x8*>(&Hout[(size_t)(row0 + lr) * OUTD + nt * 128 + cc * 8]) = v8;
        }
      }
    }
  } else {
    float* scr = reinterpret_cast<float*>(lds);   // 64 x 128 f32 = 32 KB per half
#pragma unroll
    for (int h = 0; h < 2; ++h) {
      __syncthreads();
      if (wm == h) {
#pragma unroll
        for (int m = 0; m < 4; ++m)
#pragma unroll
          for (int n = 0; n < 4; ++n)
#pragma unroll
            for (int rr = 0; rr < 4; ++rr)
              scr[(m * 16 + lq * 4 + rr) * 128 + wn * 64 + n * 16 + l15] = acc[m][n][rr] + bc[n];
      }
      __syncthreads();
#pragma unroll
      for (int i = 0; i < 8; ++i) {
        int c = t + i * 256;
        int rowp = c >> 5, cc = c & 31;
        int lr = h * 64 + rowp;
        int p0 = spos[2 * lr], p1 = spos[2 * lr + 1];
        float4 v4 = *reinterpret_cast<const float4*>(&scr[rowp * 128 + cc * 4]);
        bf16x4 s0 = *reinterpret_cast<const bf16x4*>(&slotb[(size_t)p0 * DD + nt * 128 + cc * 4]);
        bf16x4 s1 = *reinterpret_cast<const bf16x4*>(&slotb[(size_t)p1 * DD + nt * 128 + cc * 4]);
        v4.x += (float)s0[0] + (float)s1[0];
        v4.y += (float)s0[1] + (float)s1[1];
        v4.z += (float)s0[2] + (float)s1[2];
        v4.w += (float)s0[3] + (float)s1[3];
        *reinterpret_cast<float4*>(&out[(size_t)(row0 + lr) * OUTD + nt * 128 + cc * 4]) = v4;
      }
    }
  }
}

// ---------------------------------------------------------------- launch
extern "C" void kernel_launch(void* const* d_in, const int* in_sizes, int n_in,
                              void* d_out, int out_size, void* d_ws, size_t ws_size,
                              hipStream_t stream) {
  const float* x   = (const float*)d_in[0];
  const float* gw  = (const float*)d_in[1];
  const float* w1  = (const float*)d_in[2];
  const float* b1  = (const float*)d_in[3];
  const float* w2  = (const float*)d_in[4];
  const float* b2  = (const float*)d_in[5];
  const float* sw1 = (const float*)d_in[6];
  const float* sb1 = (const float*)d_in[7];
  const float* sw2 = (const float*)d_in[8];
  const float* sb2 = (const float*)d_in[9];
  float* out = (float*)d_out;

  char* ws = (char*)d_ws;
  bf16_t* xb    = (bf16_t*)(ws);                          // 16 MB  [alive through sG1]
  bf16_t* w1b   = (bf16_t*)(ws + ((size_t)16 << 20));     // 64 MB  [dead after eG1]
  bf16_t* w2b   = (bf16_t*)(ws + ((size_t)80 << 20));     // 64 MB  [dead after eG2]
  bf16_t* sw1b  = (bf16_t*)(ws + ((size_t)144 << 20));    // 8 MB
  bf16_t* sw2b  = (bf16_t*)(ws + ((size_t)152 << 20));    // 8 MB
  bf16_t* Hbuf  = (bf16_t*)(ws + ((size_t)160 << 20));    // 128 MB (16384 x 4096 bf16)
  bf16_t* slotb = (bf16_t*)(ws + ((size_t)16 << 20));     // 32 MB bf16, reuses w1b (dead by eG2)
  float*  topkw = (float*)(ws + ((size_t)288 << 20));     // 64 KB
  int*    slote = (int*)(ws + ((size_t)288 << 20) + 65536);
  int*    perm  = (int*)(ws + ((size_t)288 << 20) + 2 * 65536);
  int*    pos   = (int*)(ws + ((size_t)288 << 20) + 3 * 65536);
  int*    routing = (int*)(ws + ((size_t)288 << 20) + 4 * 65536);

  // fp32 -> bf16 weight conversions (x is converted inside gate_kernel)
  cvt_f32_bf16<<<(8 * FF * DD / 8 + 255) / 256, 256, 0, stream>>>(w1, w1b, 8 * FF * DD / 8);
  cvt_f32_bf16<<<(8 * DD * FF / 8 + 255) / 256, 256, 0, stream>>>(w2, w2b, 8 * DD * FF / 8);
  cvt_f32_bf16<<<(FF * DD / 8 + 255) / 256, 256, 0, stream>>>(sw1, sw1b, FF * DD / 8);
  cvt_f32_bf16<<<(DD * FF / 8 + 255) / 256, 256, 0, stream>>>(sw2, sw2b, DD * FF / 8);

  // routing (no global atomics anywhere; single fused kernel)
  gate_kernel<<<TT / 4, 256, 0, stream>>>(x, gw, topkw, slote, xb);
  route_kernel<<<8, 256, 0, stream>>>(slote, routing, perm, pos);

  // expert pipeline first (frees w1b for slotb), then shared with fused combine
  gemm_kernel<0><<<136 * 32, 256, 0, stream>>>(xb, w1b, b1, Hbuf, nullptr, routing, perm, nullptr, nullptr, nullptr);
  gemm_kernel<1><<<136 * 8, 256, 0, stream>>>(Hbuf, w2b, b2, slotb, nullptr, routing, perm, topkw, nullptr, nullptr);
  gemm_kernel<2><<<64 * 32, 256, 0, stream>>>(xb, sw1b, sb1, Hbuf, nullptr, routing, perm, nullptr, nullptr, nullptr);
  gemm_kernel<3><<<64 * 8, 256, 0, stream>>>(Hbuf, sw2b, sb2, nullptr, out, routing, perm, nullptr, pos, slotb);
}